// Round 10
// baseline (212.251 us; speedup 1.0000x reference)
//
#include <hip/hip_runtime.h>
#include <hip/hip_bf16.h>
#include <math.h>

// Problem constants (b=2, s=2048, d=512, h=8, k=64, rounds=4, buckets=32, cs=64)
#define WS_ 192          // 3 * 64 (acn=1 window)
#define NEGF (-3.402823466e+38f)

typedef __attribute__((ext_vector_type(8))) short short8;
typedef __attribute__((ext_vector_type(4))) float f32x4;
typedef __attribute__((ext_vector_type(4))) unsigned int u32x4;

static __device__ __forceinline__ unsigned int f2bf(float f) {
    unsigned int u = __float_as_uint(f);
    return (u + 0x7FFFu + ((u >> 16) & 1u)) >> 16;
}
// pack f32 into (hi bf16 | lo bf16<<16), hi+lo ~ exact (rel err ~2^-16)
static __device__ __forceinline__ unsigned int packsplit(float v) {
    unsigned int h = f2bf(v);
    float hf = __uint_as_float(h << 16);
    unsigned int l = f2bf(v - hf);
    return h | (l << 16);
}
// split packed uint4-pair into hi/lo bf16 fragments via v_perm
static __device__ __forceinline__ void mkfrag(uint4 a, uint4 b, short8 &h, short8 &l) {
    u32x4 hv, lv;
    hv[0] = __builtin_amdgcn_perm(a.y, a.x, 0x05040100u);
    hv[1] = __builtin_amdgcn_perm(a.w, a.z, 0x05040100u);
    hv[2] = __builtin_amdgcn_perm(b.y, b.x, 0x05040100u);
    hv[3] = __builtin_amdgcn_perm(b.w, b.z, 0x05040100u);
    lv[0] = __builtin_amdgcn_perm(a.y, a.x, 0x07060302u);
    lv[1] = __builtin_amdgcn_perm(a.w, a.z, 0x07060302u);
    lv[2] = __builtin_amdgcn_perm(b.y, b.x, 0x07060302u);
    lv[3] = __builtin_amdgcn_perm(b.w, b.z, 0x07060302u);
    h = __builtin_bit_cast(short8, hv);
    l = __builtin_bit_cast(short8, lv);
}
static __device__ __forceinline__ unsigned int cvtpk(float lo, float hi) {
    unsigned int d;
    asm("v_cvt_pk_bf16_f32 %0, %1, %2" : "=v"(d) : "v"(lo), "v"(hi));
    return d;
}

// ---------------------------------------------------------------------------
// prep kernel = qk GEMM+hash (blocks [0,512)) UNION pack (blocks [512,2688)).
// qk GEMM: f32, A staged in LDS (k-major), W read DIRECTLY from global
// (256 B broadcast-coalesced per wave-instr; 8 KB k-slab is block-shared ->
// L1-hot).  FMA order per output = kk ascending, bit-identical to r7/r9.
// pack: xpk = split(x) coalesced; wvT/woT = split(W^T) via LDS 64x64 tiles.
// ---------------------------------------------------------------------------
__global__ __launch_bounds__(256) void prep_kernel(const float* __restrict__ A,
                                                   const float* __restrict__ Wq,
                                                   const float* __restrict__ bias,
                                                   const float* __restrict__ hv,
                                                   const float* __restrict__ Wv,
                                                   const float* __restrict__ Wo,
                                                   unsigned int* __restrict__ Cpk,
                                                   float* __restrict__ scaleQ,
                                                   int* __restrict__ loc2,
                                                   unsigned int* __restrict__ xpk,
                                                   unsigned int* __restrict__ wvT,
                                                   unsigned int* __restrict__ woT) {
    __shared__ __align__(16) unsigned int SMEM[4352];   // 17.4 KB union
    const int bid = blockIdx.x;
    const int tid = threadIdx.x;

    if (bid >= 512) {
        // ================= pack path =================
        int pb = bid - 512;
        if (pb < 2048) {
            int idx = (pb * 256 + tid) * 4;
            float4 v = *(const float4*)(A + idx);   // A == x
            uint4 pk = make_uint4(packsplit(v.x), packsplit(v.y),
                                  packsplit(v.z), packsplit(v.w));
            *(uint4*)(xpk + idx) = pk;
            return;
        }
        int wb = pb - 2048;                    // 0..127
        const float* Wsrc = (wb < 64) ? Wv : Wo;
        unsigned int* Wdst = (wb < 64) ? wvT : woT;
        int t = wb & 63;
        int k0 = (t >> 3) * 64, n0 = (t & 7) * 64;
#pragma unroll
        for (int pass = 0; pass < 16; ++pass) {
            int i = pass * 4 + (tid >> 6);      // k-offset
            int j = tid & 63;                   // n-offset
            SMEM[j * 65 + i] = packsplit(Wsrc[(size_t)(k0 + i) * 512 + n0 + j]);
        }
        __syncthreads();
#pragma unroll
        for (int pass = 0; pass < 16; ++pass) {
            int j = pass * 4 + (tid >> 6);      // n-offset
            int i = tid & 63;                   // k-offset
            Wdst[(size_t)(n0 + j) * 512 + k0 + i] = SMEM[j * 65 + i];
        }
        return;
    }

    // ================= qk GEMM + hash path =================
    float* BUF = (float*)SMEM;       // As [32][68] ; reused: QS_T -> rot
    const int m0 = (bid & 63) * 64;
    const int n0 = (bid >> 6) * 64;  // = head * 64
    const int ty = tid >> 4, tx = tid & 15;
    const int ci = tid & 7, ri = tid >> 3;
    float acc[4][4] = {};
    for (int k0 = 0; k0 < 512; k0 += 32) {
        // stage A tile (transpose to k-major [32][68])
        {
            float4 a40 = *(const float4*)(A + (size_t)(m0 + ri) * 512 + k0 + ci * 4);
            float4 a41 = *(const float4*)(A + (size_t)(m0 + ri + 32) * 512 + k0 + ci * 4);
            BUF[(ci * 4 + 0) * 68 + ri] = a40.x;
            BUF[(ci * 4 + 1) * 68 + ri] = a40.y;
            BUF[(ci * 4 + 2) * 68 + ri] = a40.z;
            BUF[(ci * 4 + 3) * 68 + ri] = a40.w;
            BUF[(ci * 4 + 0) * 68 + ri + 32] = a41.x;
            BUF[(ci * 4 + 1) * 68 + ri + 32] = a41.y;
            BUF[(ci * 4 + 2) * 68 + ri + 32] = a41.z;
            BUF[(ci * 4 + 3) * 68 + ri + 32] = a41.w;
        }
        __syncthreads();
        const float* wp = Wq + (size_t)k0 * 512 + n0 + tx * 4;
#pragma unroll
        for (int kq = 0; kq < 4; ++kq) {
            float4 wr[8];
#pragma unroll
            for (int u = 0; u < 8; ++u)
                wr[u] = *(const float4*)(wp + (size_t)(kq * 8 + u) * 512);
#pragma unroll
            for (int u = 0; u < 8; ++u) {
                int kk = kq * 8 + u;
                float4 a4 = *(float4*)(&BUF[kk * 68 + ty * 4]);
                float a[4] = {a4.x, a4.y, a4.z, a4.w};
                float w[4] = {wr[u].x, wr[u].y, wr[u].z, wr[u].w};
#pragma unroll
                for (int i = 0; i < 4; ++i)
#pragma unroll
                    for (int j = 0; j < 4; ++j) acc[i][j] += a[i] * w[j];
            }
        }
        __syncthreads();
    }
    // ---- epilogue: bias, qkpk, scaleQ
    const int hh = n0 >> 6;
#pragma unroll
    for (int i = 0; i < 4; ++i) {
        int m = m0 + ty * 4 + i;
        int b = m >> 11, s = m & 2047;
        float v0 = acc[i][0] + bias[n0 + tx * 4 + 0];
        float v1 = acc[i][1] + bias[n0 + tx * 4 + 1];
        float v2 = acc[i][2] + bias[n0 + tx * 4 + 2];
        float v3 = acc[i][3] + bias[n0 + tx * 4 + 3];
        acc[i][0] = v0; acc[i][1] = v1; acc[i][2] = v2; acc[i][3] = v3;
        size_t base = ((size_t)(((b << 3) + hh) * 2048 + s)) * 64 + tx * 4;
        uint4 pk = make_uint4(packsplit(v0), packsplit(v1), packsplit(v2), packsplit(v3));
        *(uint4*)(Cpk + base) = pk;
        float sq = v0 * v0 + v1 * v1 + v2 * v2 + v3 * v3;
        sq += __shfl_xor(sq, 1, 16); sq += __shfl_xor(sq, 2, 16);
        sq += __shfl_xor(sq, 4, 16); sq += __shfl_xor(sq, 8, 16);
        if (tx == 0)
            scaleQ[(size_t)(((b << 3) + hh) * 2048 + s)] = 0.125f / fmaxf(sqrtf(sq), 1e-12f);
    }
    // ---- write qk^T to LDS: QS_T[f][tok ^ ((f&7)<<3)]
#pragma unroll
    for (int j = 0; j < 4; ++j) {
        int f = tx * 4 + j;
        int xm = (f & 7) << 3;
#pragma unroll
        for (int i = 0; i < 4; ++i)
            BUF[f * 68 + ((ty * 4 + i) ^ xm)] = acc[i][j];
    }
    __syncthreads();
    // ---- rot[tok][vr] = sum_f qk[tok][f] * hv[f][vr]   (hv from global/L2)
    const float* hvb = hv + (size_t)hh * 4096 + tx * 4;
    float rt[4][4] = {};
#pragma unroll 4
    for (int f = 0; f < 64; ++f) {
        float4 q4 = *(float4*)(&BUF[f * 68 + ((ty * 4) ^ ((f & 7) << 3))]);
        float4 h4 = *(const float4*)(hvb + f * 64);
        float q[4] = {q4.x, q4.y, q4.z, q4.w};
        float hw[4] = {h4.x, h4.y, h4.z, h4.w};
#pragma unroll
        for (int i = 0; i < 4; ++i)
#pragma unroll
            for (int j = 0; j < 4; ++j) rt[i][j] += q[i] * hw[j];
    }
    __syncthreads();   // QS_T reads done -> safe to overwrite with rot
#pragma unroll
    for (int i = 0; i < 4; ++i)
        *(float4*)(&BUF[(ty * 4 + i) * 68 + tx * 4]) =
            make_float4(rt[i][0], rt[i][1], rt[i][2], rt[i][3]);
    __syncthreads();
    // ---- argmax over concat(-rot, rot), first-occurrence tie-break
    {
        const int tok = tid >> 2, rr2 = tid & 3;
        float best = -BUF[tok * 68 + rr2];
        int bj = 0;
        for (int j = 1; j < 16; ++j) {
            float v = BUF[tok * 68 + j * 4 + rr2];
            if (-v > best) { best = -v; bj = j; }
        }
        for (int j = 0; j < 16; ++j) {
            float v = BUF[tok * 68 + j * 4 + rr2];
            if (v > best) { best = v; bj = 16 + j; }
        }
        int m = m0 + tok;
        int b = m >> 11, s = m & 2047;
        loc2[((size_t)(((b << 3) + hh) * 2048 + s)) * 4 + rr2] = bj;
    }
}

// ---------------------------------------------------------------------------
// split-bf16 MFMA GEMM (3-term): C = A(4096x512,packed) @ B^T-tile + bias.
// mode 0: write bf16 to (b,h,s,k) layout (v path); mode 1: f32 row-major.
// ---------------------------------------------------------------------------
__global__ __launch_bounds__(256) void gemm_pk(const unsigned int* __restrict__ Apk,
                                               const unsigned int* __restrict__ BT,
                                               const float* __restrict__ bias,
                                               void* __restrict__ Cout, int mode) {
    __shared__ __align__(16) unsigned int As[64 * 32];
    __shared__ __align__(16) unsigned int Bs[64 * 32];
    const int m0 = blockIdx.x * 64;
    const int n0 = blockIdx.y * 64;
    const int tid = threadIdx.x;
    const int lane = tid & 63, wv = tid >> 6;
    const int lx = lane & 15, hi = lane >> 4;
    f32x4 acc[4] = {{0.f,0.f,0.f,0.f},{0.f,0.f,0.f,0.f},{0.f,0.f,0.f,0.f},{0.f,0.f,0.f,0.f}};
    for (int k0 = 0; k0 < 512; k0 += 32) {
#pragma unroll
        for (int u = 0; u < 2; ++u) {
            int qi = u * 256 + tid;
            int row = qi >> 3, qd = qi & 7;
            uint4 a = *(const uint4*)(Apk + (size_t)(m0 + row) * 512 + k0 + qd * 4);
            *(uint4*)(&As[row * 32 + ((qd ^ (row & 7)) << 2)]) = a;
            uint4 b = *(const uint4*)(BT + (size_t)(n0 + row) * 512 + k0 + qd * 4);
            *(uint4*)(&Bs[row * 32 + ((qd ^ (row & 7)) << 2)]) = b;
        }
        __syncthreads();
        int arow = wv * 16 + lx;
        uint4 a0 = *(uint4*)(&As[arow * 32 + (((2 * hi) ^ (arow & 7)) << 2)]);
        uint4 a1 = *(uint4*)(&As[arow * 32 + (((2 * hi + 1) ^ (arow & 7)) << 2)]);
        short8 Ah, Al; mkfrag(a0, a1, Ah, Al);
#pragma unroll
        for (int j = 0; j < 4; ++j) {
            int brow = j * 16 + lx;
            uint4 b0 = *(uint4*)(&Bs[brow * 32 + (((2 * hi) ^ (brow & 7)) << 2)]);
            uint4 b1 = *(uint4*)(&Bs[brow * 32 + (((2 * hi + 1) ^ (brow & 7)) << 2)]);
            short8 Bh2, Bl2; mkfrag(b0, b1, Bh2, Bl2);
            acc[j] = __builtin_amdgcn_mfma_f32_16x16x32_bf16(Ah, Bh2, acc[j], 0, 0, 0);
            acc[j] = __builtin_amdgcn_mfma_f32_16x16x32_bf16(Ah, Bl2, acc[j], 0, 0, 0);
            acc[j] = __builtin_amdgcn_mfma_f32_16x16x32_bf16(Al, Bh2, acc[j], 0, 0, 0);
        }
        __syncthreads();
    }
#pragma unroll
    for (int j = 0; j < 4; ++j) {
        int nn = n0 + j * 16 + lx;
        float bs = bias[nn];
#pragma unroll
        for (int reg = 0; reg < 4; ++reg) {
            int m = m0 + wv * 16 + hi * 4 + reg;
            float val = acc[j][reg] + bs;
            if (mode == 0) {
                int b = m >> 11, ss = m & 2047;
                int hh = nn >> 6, f = nn & 63;
                ((unsigned short*)Cout)[((size_t)(((b << 3) + hh) * 2048 + ss)) * 64 + f] =
                    (unsigned short)f2bf(val);
            } else {
                ((float*)Cout)[(size_t)m * 512 + nn] = val;
            }
        }
    }
}

// ---------------------------------------------------------------------------
// Stable counting sort (unchanged): one 1024-thread block per (b,h,r).
// ---------------------------------------------------------------------------
__global__ __launch_bounds__(1024) void sort_kernel(const int* __restrict__ loc2,
                                                    int* __restrict__ st) {
    __shared__ int hist[32][32];
    __shared__ int off[32][32];
    __shared__ int base[32];
    const int gid = blockIdx.x;    // = bh*4 + r
    const int r = gid & 3, bh = gid >> 2;
    const int tid = threadIdx.x;
    const int lane = tid & 63, wvi = tid >> 6;
    const unsigned long long lower_mask =
        (lane == 0) ? 0ull : ((~0ull) >> (64 - lane));

    int myb[2], myrank[2];
#pragma unroll
    for (int si = 0; si < 2; ++si) {
        int seg = wvi * 2 + si;
        int p = seg * 64 + lane;
        int b = loc2[(size_t)(bh * 2048 + p) * 4 + r];
        myb[si] = b;
        myrank[si] = 0;
#pragma unroll 1
        for (int bkt = 0; bkt < 32; ++bkt) {
            unsigned long long m = __ballot(b == bkt);
            if (b == bkt) myrank[si] = __popcll(m & lower_mask);
            if (lane == bkt) hist[seg][bkt] = __popcll(m);
        }
    }
    __syncthreads();
    if (tid < 32) {
        int running = 0;
#pragma unroll 1
        for (int seg = 0; seg < 32; ++seg) {
            off[seg][tid] = running;
            running += hist[seg][tid];
        }
        base[tid] = running;
    }
    __syncthreads();
    if (tid == 0) {
        int acc = 0;
#pragma unroll 1
        for (int b = 0; b < 32; ++b) { int h = base[b]; base[b] = acc; acc += h; }
    }
    __syncthreads();
#pragma unroll
    for (int si = 0; si < 2; ++si) {
        int seg = wvi * 2 + si;
        int p = seg * 64 + lane;
        int b = myb[si];
        st[(size_t)gid * 2048 + base[b] + off[seg][b] + myrank[si]] = p;
    }
}

// ---------------------------------------------------------------------------
// Chunked attention v6 (unchanged from round 9).
// ---------------------------------------------------------------------------
#define KQUAD(row, qd) (((row) << 6) + ((((qd) ^ ((row) & 15))) << 2))
#define PBASE 6400

__global__ __launch_bounds__(256, 3) void attn_kernel(const unsigned int* __restrict__ qkpk,
                                                      const unsigned short* __restrict__ vpk,
                                                      const float* __restrict__ scaleQ,
                                                      const int* __restrict__ loc2,
                                                      const int* __restrict__ st,
                                                      float* __restrict__ lseg,
                                                      float* __restrict__ vog) {
    __shared__ __align__(16) unsigned int U[12800];  // K (12288) -> V^T + P
    __shared__ float scaleK[WS_];
    __shared__ int Tk[WS_];
    __shared__ int Lp[WS_];

    const int gid = blockIdx.x;
    const int n = gid & 31;
    const int r = (gid >> 5) & 3;
    const int bh = gid >> 7;
    const int tid = threadIdx.x;
    const int sbase = (bh * 4 + r) * 2048;
    const int lane = tid & 63;
    const int wv = tid >> 6;
    const int lx = lane & 15;
    const int hi = lane >> 4;

    if (tid < WS_) {
        int w = tid;
        int chunk = (n + 31 + (w >> 6)) & 31;
        int t = st[(size_t)sbase + chunk * 64 + (w & 63)];
        Tk[w] = t;
        int4 l4 = *(const int4*)(loc2 + (size_t)(bh * 2048 + t) * 4);
        Lp[w] = l4.x | (l4.y << 8) | (l4.z << 16) | (l4.w << 24);
        scaleK[w] = scaleQ[bh * 2048 + t];
    }
    __syncthreads();

    // ---- stage K (pre-packed)
    const int fs = tid & 15, wsb = tid >> 4;
#pragma unroll
    for (int it = 0; it < 12; ++it) {
        int row = it * 16 + wsb;
        uint4 v4 = *(const uint4*)(qkpk + ((size_t)(bh * 2048 + Tk[row])) * 64 + fs * 4);
        *(uint4*)(&U[KQUAD(row, fs)]) = v4;
    }
    __syncthreads();

    // ---- QK^T (swapped): S^T[c][q]
    const int qw = 64 + wv * 16 + lx;
    short8 Bh[2], Bl[2];
#pragma unroll
    for (int ks = 0; ks < 2; ++ks) {
        int qd0 = ks * 8 + hi * 2;
        uint4 a = *(const uint4*)(&U[KQUAD(qw, qd0)]);
        uint4 b = *(const uint4*)(&U[KQUAD(qw, qd0 + 1)]);
        mkfrag(a, b, Bh[ks], Bl[ks]);
    }
    f32x4 s[12];
    __builtin_amdgcn_s_setprio(1);
#pragma unroll
    for (int ct = 0; ct < 12; ++ct) {
        f32x4 acc = {0.f, 0.f, 0.f, 0.f};
#pragma unroll
        for (int ks = 0; ks < 2; ++ks) {
            int arow = ct * 16 + lx;
            int qd0 = ks * 8 + hi * 2;
            uint4 a = *(const uint4*)(&U[KQUAD(arow, qd0)]);
            uint4 b = *(const uint4*)(&U[KQUAD(arow, qd0 + 1)]);
            short8 Ah, Al; mkfrag(a, b, Ah, Al);
            acc = __builtin_amdgcn_mfma_f32_16x16x32_bf16(Ah, Bh[ks], acc, 0, 0, 0);
            acc = __builtin_amdgcn_mfma_f32_16x16x32_bf16(Ah, Bl[ks], acc, 0, 0, 0);
            acc = __builtin_amdgcn_mfma_f32_16x16x32_bf16(Al, Bh[ks], acc, 0, 0, 0);
        }
        s[ct] = acc;
    }
    __builtin_amdgcn_s_setprio(0);

    // issue V loads early (hide HBM/L2 latency under softmax)
    uint4 vl0[3], vl1[3];
#pragma unroll
    for (int it = 0; it < 3; ++it) {
        int idx = it * 256 + tid;
        int pr = idx >> 3, oct = idx & 7;
        vl0[it] = *(const uint4*)(vpk + ((size_t)(bh * 2048 + Tk[pr * 2])) * 64 + oct * 8);
        vl1[it] = *(const uint4*)(vpk + ((size_t)(bh * 2048 + Tk[pr * 2 + 1])) * 64 + oct * 8);
    }
    __syncthreads();   // K reads done; U reusable

    // ---- masks + register softmax (lane owns q = qw, 48 c-values)
    const int lq = Lp[qw];
    const unsigned int bmask = 0x80u << (r * 8);
    float mx = -3.0e38f;
#pragma unroll
    for (int ct = 0; ct < 12; ++ct) {
#pragma unroll
        for (int rr = 0; rr < 4; ++rr) {
            int c = ct * 16 + hi * 4 + rr;
            float val = s[ct][rr] * scaleK[c];
            unsigned int x = (unsigned int)(lq ^ Lp[c]);
            unsigned int z = ((x & 0x7f7f7f7fu) + 0x7f7f7f7fu) | x;
            unsigned int zm = ~z & 0x80808080u;
            int dup = __popc(zm);
            val = (c == qw) ? -100000.0f : val;
            val = (zm & bmask) ? val : NEGF;
            float ld = (dup < 2) ? 0.0f
                     : (dup == 2) ? 0.69314718f
                     : (dup == 3) ? 1.09861229f : 1.38629436f;
            val -= ld;
            s[ct][rr] = val;
            mx = fmaxf(mx, val);
        }
    }
    mx = fmaxf(mx, __shfl_xor(mx, 16));
    mx = fmaxf(mx, __shfl_xor(mx, 32));
    float ssum = 0.f;
#pragma unroll
    for (int ct = 0; ct < 12; ++ct)
#pragma unroll
        for (int rr = 0; rr < 4; ++rr) {
            float e = __expf(s[ct][rr] - mx);
            s[ct][rr] = e;
            ssum += e;
        }
    ssum += __shfl_xor(ssum, 16);
    ssum += __shfl_xor(ssum, 32);
    float lse = mx + __logf(ssum);
    if (hi == 0) lseg[(size_t)sbase + Tk[qw]] = lse;
    float inv = 1.0f / ssum;

    // ---- stage V^T bf16 into U[0..6400): word = f*100 + quad<<2 + w,
    //      quad = (c0>>3) ^ (f&7) ^ (f>>3); interleave via v_perm
#pragma unroll
    for (int it = 0; it < 3; ++it) {
        int idx = it * 256 + tid;
        int pr = idx >> 3, oct = idx & 7;
        int c0 = pr * 2;
        unsigned int aw[4] = {vl0[it].x, vl0[it].y, vl0[it].z, vl0[it].w};
        unsigned int bw[4] = {vl1[it].x, vl1[it].y, vl1[it].z, vl1[it].w};
#pragma unroll
        for (int j = 0; j < 8; ++j) {
            int f = oct * 8 + j;
            unsigned int w2 = (j & 1)
                ? __builtin_amdgcn_perm(bw[j >> 1], aw[j >> 1], 0x07060302u)
                : __builtin_amdgcn_perm(bw[j >> 1], aw[j >> 1], 0x05040100u);
            int quad = (c0 >> 3) ^ (f & 7) ^ (f >> 3);
            U[f * 100 + (quad << 2) + ((c0 & 7) >> 1)] = w2;
        }
    }
    // ---- P[q][c] bf16 into U[PBASE..): word = q*100 + ((c>>1) ^ ((q&3)<<3))
    const int q = wv * 16 + lx;
    const int pxm = (q & 3) << 3;
#pragma unroll
    for (int ct = 0; ct < 12; ++ct) {
        int po = ct * 8 + hi * 2;
        U[PBASE + q * 100 + ((po + 0) ^ pxm)] = cvtpk(s[ct][0] * inv, s[ct][1] * inv);
        U[PBASE + q * 100 + ((po + 1) ^ pxm)] = cvtpk(s[ct][2] * inv, s[ct][3] * inv);
    }
    __syncthreads();

    // ---- PV: O^T[f][q] = V^T . P^T, single-MFMA bf16
    f32x4 o[4] = {{0.f,0.f,0.f,0.f},{0.f,0.f,0.f,0.f},{0.f,0.f,0.f,0.f},{0.f,0.f,0.f,0.f}};
    const unsigned short* Uh = (const unsigned short*)U;
    __builtin_amdgcn_s_setprio(1);
#pragma unroll
    for (int ks = 0; ks < 6; ++ks) {
        short8 P8 = *(const short8*)(Uh + PBASE * 2 + q * 200 +
                                     (((ks * 16 + hi * 4) ^ pxm) << 1));
#pragma unroll
        for (int ft = 0; ft < 4; ++ft) {
            int f = ft * 16 + lx;
            int quad = (4 * ks + hi) ^ (f & 7) ^ (f >> 3);
            short8 V8 = *(const short8*)(Uh + f * 200 + (quad << 3));
            o[ft] = __builtin_amdgcn_mfma_f32_16x16x32_bf16(V8, P8, o[ft], 0, 0, 0);
        }
    }
    __builtin_amdgcn_s_setprio(0);
    const int tko = Tk[qw];
#pragma unroll
    for (int ft = 0; ft < 4; ++ft) {
        float4 w4 = make_float4(o[ft][0], o[ft][1], o[ft][2], o[ft][3]);
        *(float4*)(vog + ((size_t)sbase + tko) * 64 + ft * 16 + hi * 4) = w4;
    }
}

// ---------------------------------------------------------------------------
// Combine rounds -> packed split att; vectorized x4 (float4/uint4).
// ---------------------------------------------------------------------------
__global__ __launch_bounds__(256) void combine_kernel(const float* __restrict__ vog,
                                                      const float* __restrict__ lseg,
                                                      unsigned int* __restrict__ attpk) {
    const int gid = blockIdx.x * 256 + threadIdx.x;   // 524288 total
    const int kq = gid & 15;          // k-quad
    const int t = (gid >> 4) & 2047;
    const int bh = gid >> 15;
    const int b = bh >> 3, h = bh & 7;
    float l[4];
    float4 vo[4];
#pragma unroll
    for (int r = 0; r < 4; ++r) {
        l[r] = lseg[(size_t)(bh * 4 + r) * 2048 + t];
        vo[r] = *(const float4*)(vog + ((size_t)(bh * 4 + r) * 2048 + t) * 64 + kq * 4);
    }
    float m = fmaxf(fmaxf(l[0], l[1]), fmaxf(l[2], l[3]));
    float ss = expf(l[0] - m) + expf(l[1] - m) + expf(l[2] - m) + expf(l[3] - m);
    float lt = m + logf(ss);
    float o0 = 0.f, o1 = 0.f, o2 = 0.f, o3 = 0.f;
#pragma unroll
    for (int r = 0; r < 4; ++r) {
        float w = expf(l[r] - lt);
        o0 += w * vo[r].x; o1 += w * vo[r].y; o2 += w * vo[r].z; o3 += w * vo[r].w;
    }
    uint4 pk = make_uint4(packsplit(o0), packsplit(o1), packsplit(o2), packsplit(o3));
    *(uint4*)(attpk + ((size_t)(b * 2048 + t)) * 512 + h * 64 + kq * 4) = pk;
}

// ---------------------------------------------------------------------------
extern "C" void kernel_launch(void* const* d_in, const int* in_sizes, int n_in,
                              void* d_out, int out_size, void* d_ws, size_t ws_size,
                              hipStream_t stream) {
    const float* x  = (const float*)d_in[0];
    const float* Wq = (const float*)d_in[1];
    const float* bq = (const float*)d_in[2];
    const float* Wv = (const float*)d_in[3];
    const float* bv = (const float*)d_in[4];
    const float* Wo = (const float*)d_in[5];
    const float* bo = (const float*)d_in[6];
    const float* hv = (const float*)d_in[7];

    unsigned int* W = (unsigned int*)d_ws;
    float*          vog    = (float*)W;                         // [0, 8388608) f32
    unsigned int*   xpk    = W + 2097152;                       // alias - dead after v-gemm
    unsigned int*   qkpk   = W + 8388608;                       // 2097152
    unsigned short* vpk    = (unsigned short*)(W + 10485760);   // 2097152 ushort (1M u32)
    unsigned int*   attpk  = W + 11534336;                      // 2097152
    float*          scaleQ = (float*)(W + 13631488);            // 32768
    int*            loc2   = (int*)(W + 13664256);              // 131072
    int*            stbuf  = (int*)(W + 13795328);              // 131072
    float*          lseg   = (float*)(W + 13926400);            // 131072
    unsigned int*   wvT    = W + 14057472;                      // 262144
    unsigned int*   woT    = W + 14319616;                      // 262144

    dim3 gg(64, 8), blk(256);
    prep_kernel<<<2688, 256, 0, stream>>>(x, Wq, bq, hv, Wv, Wo,
                                          qkpk, scaleQ, loc2, xpk, wvT, woT);
    gemm_pk<<<gg, blk, 0, stream>>>(xpk, wvT, bv, (void*)vpk, 0);
    sort_kernel<<<64, 1024, 0, stream>>>(loc2, stbuf);
    attn_kernel<<<2048, 256, 0, stream>>>(qkpk, vpk, scaleQ, loc2, stbuf, lseg, vog);
    combine_kernel<<<2048, 256, 0, stream>>>(vog, lseg, attpk);
    gemm_pk<<<gg, blk, 0, stream>>>(attpk, woT, bo, d_out, 1);
}

// Round 11
// 147.534 us; speedup vs baseline: 1.4387x; 1.4387x over previous
//
#include <hip/hip_runtime.h>
#include <hip/hip_bf16.h>
#include <math.h>

// Problem constants (b=2, s=2048, d=512, h=8, k=64, rounds=4, buckets=32, cs=64)
#define WS_ 192          // 3 * 64 (acn=1 window)
#define NEGF (-3.402823466e+38f)

typedef __attribute__((ext_vector_type(8))) short short8;
typedef __attribute__((ext_vector_type(4))) float f32x4;
typedef __attribute__((ext_vector_type(4))) unsigned int u32x4;

static __device__ __forceinline__ unsigned int f2bf(float f) {
    unsigned int u = __float_as_uint(f);
    return (u + 0x7FFFu + ((u >> 16) & 1u)) >> 16;
}
// pack f32 into (hi bf16 | lo bf16<<16), hi+lo ~ exact (rel err ~2^-16)
static __device__ __forceinline__ unsigned int packsplit(float v) {
    unsigned int h = f2bf(v);
    float hf = __uint_as_float(h << 16);
    unsigned int l = f2bf(v - hf);
    return h | (l << 16);
}
// split packed uint4-pair into hi/lo bf16 fragments via v_perm
static __device__ __forceinline__ void mkfrag(uint4 a, uint4 b, short8 &h, short8 &l) {
    u32x4 hv, lv;
    hv[0] = __builtin_amdgcn_perm(a.y, a.x, 0x05040100u);
    hv[1] = __builtin_amdgcn_perm(a.w, a.z, 0x05040100u);
    hv[2] = __builtin_amdgcn_perm(b.y, b.x, 0x05040100u);
    hv[3] = __builtin_amdgcn_perm(b.w, b.z, 0x05040100u);
    lv[0] = __builtin_amdgcn_perm(a.y, a.x, 0x07060302u);
    lv[1] = __builtin_amdgcn_perm(a.w, a.z, 0x07060302u);
    lv[2] = __builtin_amdgcn_perm(b.y, b.x, 0x07060302u);
    lv[3] = __builtin_amdgcn_perm(b.w, b.z, 0x07060302u);
    h = __builtin_bit_cast(short8, hv);
    l = __builtin_bit_cast(short8, lv);
}
static __device__ __forceinline__ unsigned int cvtpk(float lo, float hi) {
    unsigned int d;
    asm("v_cvt_pk_bf16_f32 %0, %1, %2" : "=v"(d) : "v"(lo), "v"(hi));
    return d;
}
// async global -> LDS, 16 B per lane; lds base must be wave-uniform
static __device__ __forceinline__ void gload_lds16(const void* g, void* l) {
    __builtin_amdgcn_global_load_lds(
        (const __attribute__((address_space(1))) void*)g,
        (__attribute__((address_space(3))) void*)l, 16, 0, 0);
}

// ---------------------------------------------------------------------------
// pack kernel (r9):
//   blocks [0,2048):  xpk = split(x), 4 elems/thread, fully coalesced
//   blocks [2048,2176): wvT/woT = split(W^T) via LDS-tiled 64x64 transpose
// ---------------------------------------------------------------------------
__global__ __launch_bounds__(256) void pack_kernel(const float* __restrict__ x,
                                                   const float* __restrict__ Wv,
                                                   const float* __restrict__ Wo,
                                                   unsigned int* __restrict__ xpk,
                                                   unsigned int* __restrict__ wvT,
                                                   unsigned int* __restrict__ woT) {
    __shared__ unsigned int T[64][65];
    const int bid = blockIdx.x;
    const int tid = threadIdx.x;
    if (bid < 2048) {
        int idx = (bid * 256 + tid) * 4;
        float4 v = *(const float4*)(x + idx);
        uint4 pk = make_uint4(packsplit(v.x), packsplit(v.y), packsplit(v.z), packsplit(v.w));
        *(uint4*)(xpk + idx) = pk;
        return;
    }
    int wb = bid - 2048;                    // 0..127
    const float* Wsrc = (wb < 64) ? Wv : Wo;
    unsigned int* Wdst = (wb < 64) ? wvT : woT;
    int t = wb & 63;
    int k0 = (t >> 3) * 64, n0 = (t & 7) * 64;
#pragma unroll
    for (int pass = 0; pass < 16; ++pass) {
        int i = pass * 4 + (tid >> 6);      // k-offset
        int j = tid & 63;                   // n-offset
        T[j][i] = packsplit(Wsrc[(size_t)(k0 + i) * 512 + n0 + j]);
    }
    __syncthreads();
#pragma unroll
    for (int pass = 0; pass < 16; ++pass) {
        int j = pass * 4 + (tid >> 6);      // n-offset
        int i = tid & 63;                   // k-offset
        Wdst[(size_t)(n0 + j) * 512 + k0 + i] = T[j][i];
    }
}

// ---------------------------------------------------------------------------
// f32 GEMM for qk + FUSED LSH hash (r7/r9 version — final form).
// LDS 17.4 KB; hv read from global (L2-resident).  Hash math bit-identical
// to the passing r5-r9 versions.
// ---------------------------------------------------------------------------
__global__ __launch_bounds__(256) void gemm_qk_hash(const float* __restrict__ A,
                                                    const float* __restrict__ W,
                                                    const float* __restrict__ bias,
                                                    const float* __restrict__ hv,
                                                    unsigned int* __restrict__ Cpk,
                                                    float* __restrict__ scaleQ,
                                                    int* __restrict__ loc2) {
    __shared__ float BUF[4352];      // [0,2176)=As [2176,4352)=Ws ; reused: QS_T -> rot
    float* As = BUF;                 // [32][68] k-major
    float* Ws = BUF + 2176;          // [32][68]
    const int m0 = blockIdx.x * 64;
    const int n0 = blockIdx.y * 64;  // = head * 64
    const int tid = threadIdx.x;
    const int ty = tid >> 4, tx = tid & 15;
    const int ci = tid & 7, ri = tid >> 3;
    const int wk = tid >> 4, wt = tid & 15;
    float acc[4][4] = {};
    for (int k0 = 0; k0 < 512; k0 += 32) {
#pragma unroll
        for (int h2 = 0; h2 < 2; ++h2) {
            int i = ri + h2 * 32;
            float4 a4 = *(const float4*)(A + (size_t)(m0 + i) * 512 + k0 + ci * 4);
            As[(ci * 4 + 0) * 68 + i] = a4.x;
            As[(ci * 4 + 1) * 68 + i] = a4.y;
            As[(ci * 4 + 2) * 68 + i] = a4.z;
            As[(ci * 4 + 3) * 68 + i] = a4.w;
        }
#pragma unroll
        for (int h2 = 0; h2 < 2; ++h2) {
            int kk = wk + h2 * 16;
            float4 w4 = *(const float4*)(W + (size_t)(k0 + kk) * 512 + n0 + wt * 4);
            *(float4*)(&Ws[kk * 68 + wt * 4]) = w4;
        }
        __syncthreads();
#pragma unroll
        for (int kk = 0; kk < 32; ++kk) {
            float4 a4 = *(float4*)(&As[kk * 68 + ty * 4]);
            float4 w4 = *(float4*)(&Ws[kk * 68 + tx * 4]);
            float a[4] = {a4.x, a4.y, a4.z, a4.w};
            float w[4] = {w4.x, w4.y, w4.z, w4.w};
#pragma unroll
            for (int i = 0; i < 4; ++i)
#pragma unroll
                for (int j = 0; j < 4; ++j) acc[i][j] += a[i] * w[j];
        }
        __syncthreads();
    }
    // ---- epilogue: bias, qkpk, scaleQ (after final sync, As/Ws are free)
    const int hh = n0 >> 6;
#pragma unroll
    for (int i = 0; i < 4; ++i) {
        int m = m0 + ty * 4 + i;
        int b = m >> 11, s = m & 2047;
        float v0 = acc[i][0] + bias[n0 + tx * 4 + 0];
        float v1 = acc[i][1] + bias[n0 + tx * 4 + 1];
        float v2 = acc[i][2] + bias[n0 + tx * 4 + 2];
        float v3 = acc[i][3] + bias[n0 + tx * 4 + 3];
        acc[i][0] = v0; acc[i][1] = v1; acc[i][2] = v2; acc[i][3] = v3;
        size_t base = ((size_t)(((b << 3) + hh) * 2048 + s)) * 64 + tx * 4;
        uint4 pk = make_uint4(packsplit(v0), packsplit(v1), packsplit(v2), packsplit(v3));
        *(uint4*)(Cpk + base) = pk;
        float sq = v0 * v0 + v1 * v1 + v2 * v2 + v3 * v3;
        sq += __shfl_xor(sq, 1, 16); sq += __shfl_xor(sq, 2, 16);
        sq += __shfl_xor(sq, 4, 16); sq += __shfl_xor(sq, 8, 16);
        if (tx == 0)
            scaleQ[(size_t)(((b << 3) + hh) * 2048 + s)] = 0.125f / fmaxf(sqrtf(sq), 1e-12f);
    }
    // ---- write qk^T to LDS: QS_T[f][tok ^ ((f&7)<<3)]
#pragma unroll
    for (int j = 0; j < 4; ++j) {
        int f = tx * 4 + j;
        int xm = (f & 7) << 3;
#pragma unroll
        for (int i = 0; i < 4; ++i)
            BUF[f * 68 + ((ty * 4 + i) ^ xm)] = acc[i][j];
    }
    __syncthreads();
    // ---- rot[tok][vr] = sum_f qk[tok][f] * hv[f][vr]   (hv from global/L2)
    const float* hvb = hv + (size_t)hh * 4096 + tx * 4;
    float rt[4][4] = {};
#pragma unroll 4
    for (int f = 0; f < 64; ++f) {
        float4 q4 = *(float4*)(&BUF[f * 68 + ((ty * 4) ^ ((f & 7) << 3))]);
        float4 h4 = *(const float4*)(hvb + f * 64);
        float q[4] = {q4.x, q4.y, q4.z, q4.w};
        float hw[4] = {h4.x, h4.y, h4.z, h4.w};
#pragma unroll
        for (int i = 0; i < 4; ++i)
#pragma unroll
            for (int j = 0; j < 4; ++j) rt[i][j] += q[i] * hw[j];
    }
    __syncthreads();   // QS_T reads done -> safe to overwrite with rot
#pragma unroll
    for (int i = 0; i < 4; ++i)
        *(float4*)(&BUF[(ty * 4 + i) * 68 + tx * 4]) =
            make_float4(rt[i][0], rt[i][1], rt[i][2], rt[i][3]);
    __syncthreads();
    // ---- argmax over concat(-rot, rot), first-occurrence tie-break
    {
        const int tok = tid >> 2, rr2 = tid & 3;
        float best = -BUF[tok * 68 + rr2];
        int bj = 0;
        for (int j = 1; j < 16; ++j) {
            float v = BUF[tok * 68 + j * 4 + rr2];
            if (-v > best) { best = -v; bj = j; }
        }
        for (int j = 0; j < 16; ++j) {
            float v = BUF[tok * 68 + j * 4 + rr2];
            if (v > best) { best = v; bj = 16 + j; }
        }
        int m = m0 + tok;
        int b = m >> 11, s = m & 2047;
        loc2[((size_t)(((b << 3) + hh) * 2048 + s)) * 4 + rr2] = bj;
    }
}

// ---------------------------------------------------------------------------
// split-bf16 MFMA GEMM (3-term): C = A(4096x512,packed) @ B^T-tile + bias.
// Staging via global_load_lds (16B/lane): LDS dest is lane-LINEAR; the XOR
// swizzle is applied to the GLOBAL source quad index instead (involution ->
// stored layout identical to the old reg-staged one; read side unchanged).
// mode 0: write bf16 to (b,h,s,k) layout (v path); mode 1: f32 row-major.
// ---------------------------------------------------------------------------
__global__ __launch_bounds__(256) void gemm_pk(const unsigned int* __restrict__ Apk,
                                               const unsigned int* __restrict__ BT,
                                               const float* __restrict__ bias,
                                               void* __restrict__ Cout, int mode) {
    __shared__ __align__(16) unsigned int As[64 * 32];
    __shared__ __align__(16) unsigned int Bs[64 * 32];
    const int m0 = blockIdx.x * 64;
    const int n0 = blockIdx.y * 64;
    const int tid = threadIdx.x;
    const int lane = tid & 63, wv = tid >> 6;
    const int lx = lane & 15, hi = lane >> 4;
    const int wbase = tid & ~63;           // wave-uniform qi base (u=0)
    f32x4 acc[4] = {{0.f,0.f,0.f,0.f},{0.f,0.f,0.f,0.f},{0.f,0.f,0.f,0.f},{0.f,0.f,0.f,0.f}};
    for (int k0 = 0; k0 < 512; k0 += 32) {
#pragma unroll
        for (int u = 0; u < 2; ++u) {
            int qi = u * 256 + tid;
            int row = qi >> 3, qd = qi & 7;
            int sq = (qd ^ (row & 7)) << 2;      // pre-swizzled source quad
            gload_lds16(Apk + (size_t)(m0 + row) * 512 + k0 + sq,
                        &As[(u * 256 + wbase) * 4]);
            gload_lds16(BT + (size_t)(n0 + row) * 512 + k0 + sq,
                        &Bs[(u * 256 + wbase) * 4]);
        }
        __syncthreads();
        int arow = wv * 16 + lx;
        uint4 a0 = *(uint4*)(&As[arow * 32 + (((2 * hi) ^ (arow & 7)) << 2)]);
        uint4 a1 = *(uint4*)(&As[arow * 32 + (((2 * hi + 1) ^ (arow & 7)) << 2)]);
        short8 Ah, Al; mkfrag(a0, a1, Ah, Al);
#pragma unroll
        for (int j = 0; j < 4; ++j) {
            int brow = j * 16 + lx;
            uint4 b0 = *(uint4*)(&Bs[brow * 32 + (((2 * hi) ^ (brow & 7)) << 2)]);
            uint4 b1 = *(uint4*)(&Bs[brow * 32 + (((2 * hi + 1) ^ (brow & 7)) << 2)]);
            short8 Bh2, Bl2; mkfrag(b0, b1, Bh2, Bl2);
            acc[j] = __builtin_amdgcn_mfma_f32_16x16x32_bf16(Ah, Bh2, acc[j], 0, 0, 0);
            acc[j] = __builtin_amdgcn_mfma_f32_16x16x32_bf16(Ah, Bl2, acc[j], 0, 0, 0);
            acc[j] = __builtin_amdgcn_mfma_f32_16x16x32_bf16(Al, Bh2, acc[j], 0, 0, 0);
        }
        __syncthreads();
    }
#pragma unroll
    for (int j = 0; j < 4; ++j) {
        int nn = n0 + j * 16 + lx;
        float bs = bias[nn];
#pragma unroll
        for (int reg = 0; reg < 4; ++reg) {
            int m = m0 + wv * 16 + hi * 4 + reg;
            float val = acc[j][reg] + bs;
            if (mode == 0) {
                int b = m >> 11, ss = m & 2047;
                int hh = nn >> 6, f = nn & 63;
                ((unsigned short*)Cout)[((size_t)(((b << 3) + hh) * 2048 + ss)) * 64 + f] =
                    (unsigned short)f2bf(val);
            } else {
                ((float*)Cout)[(size_t)m * 512 + nn] = val;
            }
        }
    }
}

// ---------------------------------------------------------------------------
// Stable counting sort (unchanged): one 1024-thread block per (b,h,r).
// ---------------------------------------------------------------------------
__global__ __launch_bounds__(1024) void sort_kernel(const int* __restrict__ loc2,
                                                    int* __restrict__ st) {
    __shared__ int hist[32][32];
    __shared__ int off[32][32];
    __shared__ int base[32];
    const int gid = blockIdx.x;    // = bh*4 + r
    const int r = gid & 3, bh = gid >> 2;
    const int tid = threadIdx.x;
    const int lane = tid & 63, wvi = tid >> 6;
    const unsigned long long lower_mask =
        (lane == 0) ? 0ull : ((~0ull) >> (64 - lane));

    int myb[2], myrank[2];
#pragma unroll
    for (int si = 0; si < 2; ++si) {
        int seg = wvi * 2 + si;
        int p = seg * 64 + lane;
        int b = loc2[(size_t)(bh * 2048 + p) * 4 + r];
        myb[si] = b;
        myrank[si] = 0;
#pragma unroll 1
        for (int bkt = 0; bkt < 32; ++bkt) {
            unsigned long long m = __ballot(b == bkt);
            if (b == bkt) myrank[si] = __popcll(m & lower_mask);
            if (lane == bkt) hist[seg][bkt] = __popcll(m);
        }
    }
    __syncthreads();
    if (tid < 32) {
        int running = 0;
#pragma unroll 1
        for (int seg = 0; seg < 32; ++seg) {
            off[seg][tid] = running;
            running += hist[seg][tid];
        }
        base[tid] = running;
    }
    __syncthreads();
    if (tid == 0) {
        int acc = 0;
#pragma unroll 1
        for (int b = 0; b < 32; ++b) { int h = base[b]; base[b] = acc; acc += h; }
    }
    __syncthreads();
#pragma unroll
    for (int si = 0; si < 2; ++si) {
        int seg = wvi * 2 + si;
        int p = seg * 64 + lane;
        int b = myb[si];
        st[(size_t)gid * 2048 + base[b] + off[seg][b] + myrank[si]] = p;
    }
}

// ---------------------------------------------------------------------------
// Chunked attention v6 (unchanged from round 9).
// ---------------------------------------------------------------------------
#define KQUAD(row, qd) (((row) << 6) + ((((qd) ^ ((row) & 15))) << 2))
#define PBASE 6400

__global__ __launch_bounds__(256, 3) void attn_kernel(const unsigned int* __restrict__ qkpk,
                                                      const unsigned short* __restrict__ vpk,
                                                      const float* __restrict__ scaleQ,
                                                      const int* __restrict__ loc2,
                                                      const int* __restrict__ st,
                                                      float* __restrict__ lseg,
                                                      float* __restrict__ vog) {
    __shared__ __align__(16) unsigned int U[12800];  // K (12288) -> V^T + P
    __shared__ float scaleK[WS_];
    __shared__ int Tk[WS_];
    __shared__ int Lp[WS_];

    const int gid = blockIdx.x;
    const int n = gid & 31;
    const int r = (gid >> 5) & 3;
    const int bh = gid >> 7;
    const int tid = threadIdx.x;
    const int sbase = (bh * 4 + r) * 2048;
    const int lane = tid & 63;
    const int wv = tid >> 6;
    const int lx = lane & 15;
    const int hi = lane >> 4;

    if (tid < WS_) {
        int w = tid;
        int chunk = (n + 31 + (w >> 6)) & 31;
        int t = st[(size_t)sbase + chunk * 64 + (w & 63)];
        Tk[w] = t;
        int4 l4 = *(const int4*)(loc2 + (size_t)(bh * 2048 + t) * 4);
        Lp[w] = l4.x | (l4.y << 8) | (l4.z << 16) | (l4.w << 24);
        scaleK[w] = scaleQ[bh * 2048 + t];
    }
    __syncthreads();

    // ---- stage K (pre-packed)
    const int fs = tid & 15, wsb = tid >> 4;
#pragma unroll
    for (int it = 0; it < 12; ++it) {
        int row = it * 16 + wsb;
        uint4 v4 = *(const uint4*)(qkpk + ((size_t)(bh * 2048 + Tk[row])) * 64 + fs * 4);
        *(uint4*)(&U[KQUAD(row, fs)]) = v4;
    }
    __syncthreads();

    // ---- QK^T (swapped): S^T[c][q]
    const int qw = 64 + wv * 16 + lx;
    short8 Bh[2], Bl[2];
#pragma unroll
    for (int ks = 0; ks < 2; ++ks) {
        int qd0 = ks * 8 + hi * 2;
        uint4 a = *(const uint4*)(&U[KQUAD(qw, qd0)]);
        uint4 b = *(const uint4*)(&U[KQUAD(qw, qd0 + 1)]);
        mkfrag(a, b, Bh[ks], Bl[ks]);
    }
    f32x4 s[12];
    __builtin_amdgcn_s_setprio(1);
#pragma unroll
    for (int ct = 0; ct < 12; ++ct) {
        f32x4 acc = {0.f, 0.f, 0.f, 0.f};
#pragma unroll
        for (int ks = 0; ks < 2; ++ks) {
            int arow = ct * 16 + lx;
            int qd0 = ks * 8 + hi * 2;
            uint4 a = *(const uint4*)(&U[KQUAD(arow, qd0)]);
            uint4 b = *(const uint4*)(&U[KQUAD(arow, qd0 + 1)]);
            short8 Ah, Al; mkfrag(a, b, Ah, Al);
            acc = __builtin_amdgcn_mfma_f32_16x16x32_bf16(Ah, Bh[ks], acc, 0, 0, 0);
            acc = __builtin_amdgcn_mfma_f32_16x16x32_bf16(Ah, Bl[ks], acc, 0, 0, 0);
            acc = __builtin_amdgcn_mfma_f32_16x16x32_bf16(Al, Bh[ks], acc, 0, 0, 0);
        }
        s[ct] = acc;
    }
    __builtin_amdgcn_s_setprio(0);

    // issue V loads early (hide HBM/L2 latency under softmax)
    uint4 vl0[3], vl1[3];
#pragma unroll
    for (int it = 0; it < 3; ++it) {
        int idx = it * 256 + tid;
        int pr = idx >> 3, oct = idx & 7;
        vl0[it] = *(const uint4*)(vpk + ((size_t)(bh * 2048 + Tk[pr * 2])) * 64 + oct * 8);
        vl1[it] = *(const uint4*)(vpk + ((size_t)(bh * 2048 + Tk[pr * 2 + 1])) * 64 + oct * 8);
    }
    __syncthreads();   // K reads done; U reusable

    // ---- masks + register softmax (lane owns q = qw, 48 c-values)
    const int lq = Lp[qw];
    const unsigned int bmask = 0x80u << (r * 8);
    float mx = -3.0e38f;
#pragma unroll
    for (int ct = 0; ct < 12; ++ct) {
#pragma unroll
        for (int rr = 0; rr < 4; ++rr) {
            int c = ct * 16 + hi * 4 + rr;
            float val = s[ct][rr] * scaleK[c];
            unsigned int x = (unsigned int)(lq ^ Lp[c]);
            unsigned int z = ((x & 0x7f7f7f7fu) + 0x7f7f7f7fu) | x;
            unsigned int zm = ~z & 0x80808080u;
            int dup = __popc(zm);
            val = (c == qw) ? -100000.0f : val;
            val = (zm & bmask) ? val : NEGF;
            float ld = (dup < 2) ? 0.0f
                     : (dup == 2) ? 0.69314718f
                     : (dup == 3) ? 1.09861229f : 1.38629436f;
            val -= ld;
            s[ct][rr] = val;
            mx = fmaxf(mx, val);
        }
    }
    mx = fmaxf(mx, __shfl_xor(mx, 16));
    mx = fmaxf(mx, __shfl_xor(mx, 32));
    float ssum = 0.f;
#pragma unroll
    for (int ct = 0; ct < 12; ++ct)
#pragma unroll
        for (int rr = 0; rr < 4; ++rr) {
            float e = __expf(s[ct][rr] - mx);
            s[ct][rr] = e;
            ssum += e;
        }
    ssum += __shfl_xor(ssum, 16);
    ssum += __shfl_xor(ssum, 32);
    float lse = mx + __logf(ssum);
    if (hi == 0) lseg[(size_t)sbase + Tk[qw]] = lse;
    float inv = 1.0f / ssum;

    // ---- stage V^T bf16 into U[0..6400): word = f*100 + quad<<2 + w,
    //      quad = (c0>>3) ^ (f&7) ^ (f>>3); interleave via v_perm
#pragma unroll
    for (int it = 0; it < 3; ++it) {
        int idx = it * 256 + tid;
        int pr = idx >> 3, oct = idx & 7;
        int c0 = pr * 2;
        unsigned int aw[4] = {vl0[it].x, vl0[it].y, vl0[it].z, vl0[it].w};
        unsigned int bw[4] = {vl1[it].x, vl1[it].y, vl1[it].z, vl1[it].w};
#pragma unroll
        for (int j = 0; j < 8; ++j) {
            int f = oct * 8 + j;
            unsigned int w2 = (j & 1)
                ? __builtin_amdgcn_perm(bw[j >> 1], aw[j >> 1], 0x07060302u)
                : __builtin_amdgcn_perm(bw[j >> 1], aw[j >> 1], 0x05040100u);
            int quad = (c0 >> 3) ^ (f & 7) ^ (f >> 3);
            U[f * 100 + (quad << 2) + ((c0 & 7) >> 1)] = w2;
        }
    }
    // ---- P[q][c] bf16 into U[PBASE..): word = q*100 + ((c>>1) ^ ((q&3)<<3))
    const int q = wv * 16 + lx;
    const int pxm = (q & 3) << 3;
#pragma unroll
    for (int ct = 0; ct < 12; ++ct) {
        int po = ct * 8 + hi * 2;
        U[PBASE + q * 100 + ((po + 0) ^ pxm)] = cvtpk(s[ct][0] * inv, s[ct][1] * inv);
        U[PBASE + q * 100 + ((po + 1) ^ pxm)] = cvtpk(s[ct][2] * inv, s[ct][3] * inv);
    }
    __syncthreads();

    // ---- PV: O^T[f][q] = V^T . P^T, single-MFMA bf16
    f32x4 o[4] = {{0.f,0.f,0.f,0.f},{0.f,0.f,0.f,0.f},{0.f,0.f,0.f,0.f},{0.f,0.f,0.f,0.f}};
    const unsigned short* Uh = (const unsigned short*)U;
    __builtin_amdgcn_s_setprio(1);
#pragma unroll
    for (int ks = 0; ks < 6; ++ks) {
        short8 P8 = *(const short8*)(Uh + PBASE * 2 + q * 200 +
                                     (((ks * 16 + hi * 4) ^ pxm) << 1));
#pragma unroll
        for (int ft = 0; ft < 4; ++ft) {
            int f = ft * 16 + lx;
            int quad = (4 * ks + hi) ^ (f & 7) ^ (f >> 3);
            short8 V8 = *(const short8*)(Uh + f * 200 + (quad << 3));
            o[ft] = __builtin_amdgcn_mfma_f32_16x16x32_bf16(V8, P8, o[ft], 0, 0, 0);
        }
    }
    __builtin_amdgcn_s_setprio(0);
    const int tko = Tk[qw];
#pragma unroll
    for (int ft = 0; ft < 4; ++ft) {
        float4 w4 = make_float4(o[ft][0], o[ft][1], o[ft][2], o[ft][3]);
        *(float4*)(vog + ((size_t)sbase + tko) * 64 + ft * 16 + hi * 4) = w4;
    }
}

// ---------------------------------------------------------------------------
// Combine rounds -> packed split att; vectorized x4 (float4/uint4).
// ---------------------------------------------------------------------------
__global__ __launch_bounds__(256) void combine_kernel(const float* __restrict__ vog,
                                                      const float* __restrict__ lseg,
                                                      unsigned int* __restrict__ attpk) {
    const int gid = blockIdx.x * 256 + threadIdx.x;   // 524288 total
    const int kq = gid & 15;          // k-quad
    const int t = (gid >> 4) & 2047;
    const int bh = gid >> 15;
    const int b = bh >> 3, h = bh & 7;
    float l[4];
    float4 vo[4];
#pragma unroll
    for (int r = 0; r < 4; ++r) {
        l[r] = lseg[(size_t)(bh * 4 + r) * 2048 + t];
        vo[r] = *(const float4*)(vog + ((size_t)(bh * 4 + r) * 2048 + t) * 64 + kq * 4);
    }
    float m = fmaxf(fmaxf(l[0], l[1]), fmaxf(l[2], l[3]));
    float ss = expf(l[0] - m) + expf(l[1] - m) + expf(l[2] - m) + expf(l[3] - m);
    float lt = m + logf(ss);
    float o0 = 0.f, o1 = 0.f, o2 = 0.f, o3 = 0.f;
#pragma unroll
    for (int r = 0; r < 4; ++r) {
        float w = expf(l[r] - lt);
        o0 += w * vo[r].x; o1 += w * vo[r].y; o2 += w * vo[r].z; o3 += w * vo[r].w;
    }
    uint4 pk = make_uint4(packsplit(o0), packsplit(o1), packsplit(o2), packsplit(o3));
    *(uint4*)(attpk + ((size_t)(b * 2048 + t)) * 512 + h * 64 + kq * 4) = pk;
}

// ---------------------------------------------------------------------------
extern "C" void kernel_launch(void* const* d_in, const int* in_sizes, int n_in,
                              void* d_out, int out_size, void* d_ws, size_t ws_size,
                              hipStream_t stream) {
    const float* x  = (const float*)d_in[0];
    const float* Wq = (const float*)d_in[1];
    const float* bq = (const float*)d_in[2];
    const float* Wv = (const float*)d_in[3];
    const float* bv = (const float*)d_in[4];
    const float* Wo = (const float*)d_in[5];
    const float* bo = (const float*)d_in[6];
    const float* hv = (const float*)d_in[7];

    unsigned int* W = (unsigned int*)d_ws;
    float*          vog    = (float*)W;                         // [0, 8388608) f32
    unsigned int*   xpk    = W + 2097152;                       // alias - dead after v-gemm
    unsigned int*   qkpk   = W + 8388608;                       // 2097152
    unsigned short* vpk    = (unsigned short*)(W + 10485760);   // 2097152 ushort (1M u32)
    unsigned int*   attpk  = W + 11534336;                      // 2097152
    float*          scaleQ = (float*)(W + 13631488);            // 32768
    int*            loc2   = (int*)(W + 13664256);              // 131072
    int*            stbuf  = (int*)(W + 13795328);              // 131072
    float*          lseg   = (float*)(W + 13926400);            // 131072
    unsigned int*   wvT    = W + 14057472;                      // 262144
    unsigned int*   woT    = W + 14319616;                      // 262144

    dim3 gg(64, 8), blk(256);
    pack_kernel<<<2176, 256, 0, stream>>>(x, Wv, Wo, xpk, wvT, woT);
    gemm_qk_hash<<<gg, blk, 0, stream>>>(x, Wq, bq, hv, qkpk, scaleQ, loc2);
    gemm_pk<<<gg, blk, 0, stream>>>(xpk, wvT, bv, (void*)vpk, 0);
    sort_kernel<<<64, 1024, 0, stream>>>(loc2, stbuf);
    attn_kernel<<<2048, 256, 0, stream>>>(qkpk, vpk, scaleQ, loc2, stbuf, lseg, vog);
    combine_kernel<<<2048, 256, 0, stream>>>(vog, lseg, attpk);
    gemm_pk<<<gg, blk, 0, stream>>>(attpk, woT, bo, d_out, 1);
}

// Round 12
// 146.775 us; speedup vs baseline: 1.4461x; 1.0052x over previous
//
#include <hip/hip_runtime.h>
#include <hip/hip_bf16.h>
#include <math.h>

// Problem constants (b=2, s=2048, d=512, h=8, k=64, rounds=4, buckets=32, cs=64)
#define WS_ 192          // 3 * 64 (acn=1 window)
#define NEGF (-3.402823466e+38f)

typedef __attribute__((ext_vector_type(8))) short short8;
typedef __attribute__((ext_vector_type(4))) float f32x4;
typedef __attribute__((ext_vector_type(4))) unsigned int u32x4;

static __device__ __forceinline__ unsigned int f2bf(float f) {
    unsigned int u = __float_as_uint(f);
    return (u + 0x7FFFu + ((u >> 16) & 1u)) >> 16;
}
// pack f32 into (hi bf16 | lo bf16<<16), hi+lo ~ exact (rel err ~2^-16)
static __device__ __forceinline__ unsigned int packsplit(float v) {
    unsigned int h = f2bf(v);
    float hf = __uint_as_float(h << 16);
    unsigned int l = f2bf(v - hf);
    return h | (l << 16);
}
// split packed uint4-pair into hi/lo bf16 fragments via v_perm
static __device__ __forceinline__ void mkfrag(uint4 a, uint4 b, short8 &h, short8 &l) {
    u32x4 hv, lv;
    hv[0] = __builtin_amdgcn_perm(a.y, a.x, 0x05040100u);
    hv[1] = __builtin_amdgcn_perm(a.w, a.z, 0x05040100u);
    hv[2] = __builtin_amdgcn_perm(b.y, b.x, 0x05040100u);
    hv[3] = __builtin_amdgcn_perm(b.w, b.z, 0x05040100u);
    lv[0] = __builtin_amdgcn_perm(a.y, a.x, 0x07060302u);
    lv[1] = __builtin_amdgcn_perm(a.w, a.z, 0x07060302u);
    lv[2] = __builtin_amdgcn_perm(b.y, b.x, 0x07060302u);
    lv[3] = __builtin_amdgcn_perm(b.w, b.z, 0x07060302u);
    h = __builtin_bit_cast(short8, hv);
    l = __builtin_bit_cast(short8, lv);
}
static __device__ __forceinline__ unsigned int cvtpk(float lo, float hi) {
    unsigned int d;
    asm("v_cvt_pk_bf16_f32 %0, %1, %2" : "=v"(d) : "v"(lo), "v"(hi));
    return d;
}
// async global -> LDS, 16 B per lane; lds base must be wave-uniform
static __device__ __forceinline__ void gload_lds16(const void* g, void* l) {
    __builtin_amdgcn_global_load_lds(
        (const __attribute__((address_space(1))) void*)g,
        (__attribute__((address_space(3))) void*)l, 16, 0, 0);
}

// ---------------------------------------------------------------------------
// prep kernel = qk GEMM+hash (blocks [0,512), EXACT r7 structure) UNION pack
// (blocks [512,2688), r9 structure).  qk epilogue writes qkr in the
// plane-split row format: token row = 256 B = [64 bf16 hi | 64 bf16 lo].
// Hash math bit-identical to r5-r11.
// ---------------------------------------------------------------------------
__global__ __launch_bounds__(256) void prep_kernel(const float* __restrict__ A,
                                                   const float* __restrict__ W,
                                                   const float* __restrict__ bias,
                                                   const float* __restrict__ hv,
                                                   const float* __restrict__ Wv,
                                                   const float* __restrict__ Wo,
                                                   unsigned short* __restrict__ qkr,
                                                   float* __restrict__ scaleQ,
                                                   int* __restrict__ loc2,
                                                   unsigned int* __restrict__ xpk,
                                                   unsigned int* __restrict__ wvT,
                                                   unsigned int* __restrict__ woT) {
    __shared__ float BUF[4352];      // qk: As|Ws then QS_T->rot ; pack: T[64][65]
    const int bid = blockIdx.x;
    const int tid = threadIdx.x;

    if (bid >= 512) {
        // ================= pack path (r9 body, LDS aliased) =================
        int pb = bid - 512;
        if (pb < 2048) {
            int idx = (pb * 256 + tid) * 4;
            float4 v = *(const float4*)(A + idx);   // A == x
            uint4 pk = make_uint4(packsplit(v.x), packsplit(v.y),
                                  packsplit(v.z), packsplit(v.w));
            *(uint4*)(xpk + idx) = pk;
            return;
        }
        unsigned int* T = (unsigned int*)BUF;       // [64][65]
        int wb = pb - 2048;                         // 0..127
        const float* Wsrc = (wb < 64) ? Wv : Wo;
        unsigned int* Wdst = (wb < 64) ? wvT : woT;
        int t = wb & 63;
        int k0 = (t >> 3) * 64, n0 = (t & 7) * 64;
#pragma unroll
        for (int pass = 0; pass < 16; ++pass) {
            int i = pass * 4 + (tid >> 6);      // k-offset
            int j = tid & 63;                   // n-offset
            T[j * 65 + i] = packsplit(Wsrc[(size_t)(k0 + i) * 512 + n0 + j]);
        }
        __syncthreads();
#pragma unroll
        for (int pass = 0; pass < 16; ++pass) {
            int j = pass * 4 + (tid >> 6);      // n-offset
            int i = tid & 63;                   // k-offset
            Wdst[(size_t)(n0 + j) * 512 + k0 + i] = T[j * 65 + i];
        }
        return;
    }

    // ================= qk GEMM + hash path (r7 body) =================
    float* As = BUF;                 // [32][68] k-major
    float* Ws = BUF + 2176;          // [32][68]
    const int m0 = (bid & 63) * 64;
    const int n0 = (bid >> 6) * 64;  // = head * 64
    const int ty = tid >> 4, tx = tid & 15;
    const int ci = tid & 7, ri = tid >> 3;
    const int wk = tid >> 4, wt = tid & 15;
    float acc[4][4] = {};
    for (int k0 = 0; k0 < 512; k0 += 32) {
#pragma unroll
        for (int h2 = 0; h2 < 2; ++h2) {
            int i = ri + h2 * 32;
            float4 a4 = *(const float4*)(A + (size_t)(m0 + i) * 512 + k0 + ci * 4);
            As[(ci * 4 + 0) * 68 + i] = a4.x;
            As[(ci * 4 + 1) * 68 + i] = a4.y;
            As[(ci * 4 + 2) * 68 + i] = a4.z;
            As[(ci * 4 + 3) * 68 + i] = a4.w;
        }
#pragma unroll
        for (int h2 = 0; h2 < 2; ++h2) {
            int kk = wk + h2 * 16;
            float4 w4 = *(const float4*)(W + (size_t)(k0 + kk) * 512 + n0 + wt * 4);
            *(float4*)(&Ws[kk * 68 + wt * 4]) = w4;
        }
        __syncthreads();
#pragma unroll
        for (int kk = 0; kk < 32; ++kk) {
            float4 a4 = *(float4*)(&As[kk * 68 + ty * 4]);
            float4 w4 = *(float4*)(&Ws[kk * 68 + tx * 4]);
            float a[4] = {a4.x, a4.y, a4.z, a4.w};
            float w[4] = {w4.x, w4.y, w4.z, w4.w};
#pragma unroll
            for (int i = 0; i < 4; ++i)
#pragma unroll
                for (int j = 0; j < 4; ++j) acc[i][j] += a[i] * w[j];
        }
        __syncthreads();
    }
    // ---- epilogue: bias, qkr (plane-split), scaleQ
    const int hh = n0 >> 6;
#pragma unroll
    for (int i = 0; i < 4; ++i) {
        int m = m0 + ty * 4 + i;
        int b = m >> 11, s = m & 2047;
        float v0 = acc[i][0] + bias[n0 + tx * 4 + 0];
        float v1 = acc[i][1] + bias[n0 + tx * 4 + 1];
        float v2 = acc[i][2] + bias[n0 + tx * 4 + 2];
        float v3 = acc[i][3] + bias[n0 + tx * 4 + 3];
        acc[i][0] = v0; acc[i][1] = v1; acc[i][2] = v2; acc[i][3] = v3;
        unsigned int h0 = f2bf(v0), h1 = f2bf(v1), h2v = f2bf(v2), h3 = f2bf(v3);
        unsigned int l0 = f2bf(v0 - __uint_as_float(h0 << 16));
        unsigned int l1 = f2bf(v1 - __uint_as_float(h1 << 16));
        unsigned int l2 = f2bf(v2 - __uint_as_float(h2v << 16));
        unsigned int l3 = f2bf(v3 - __uint_as_float(h3 << 16));
        size_t trow = ((size_t)(((b << 3) + hh) * 2048 + s)) * 128;
        *(uint2*)(qkr + trow + tx * 4) =
            make_uint2(h0 | (h1 << 16), h2v | (h3 << 16));
        *(uint2*)(qkr + trow + 64 + tx * 4) =
            make_uint2(l0 | (l1 << 16), l2 | (l3 << 16));
        float sq = v0 * v0 + v1 * v1 + v2 * v2 + v3 * v3;
        sq += __shfl_xor(sq, 1, 16); sq += __shfl_xor(sq, 2, 16);
        sq += __shfl_xor(sq, 4, 16); sq += __shfl_xor(sq, 8, 16);
        if (tx == 0)
            scaleQ[(size_t)(((b << 3) + hh) * 2048 + s)] = 0.125f / fmaxf(sqrtf(sq), 1e-12f);
    }
    // ---- write qk^T to LDS: QS_T[f][tok ^ ((f&7)<<3)]
#pragma unroll
    for (int j = 0; j < 4; ++j) {
        int f = tx * 4 + j;
        int xm = (f & 7) << 3;
#pragma unroll
        for (int i = 0; i < 4; ++i)
            BUF[f * 68 + ((ty * 4 + i) ^ xm)] = acc[i][j];
    }
    __syncthreads();
    // ---- rot[tok][vr] = sum_f qk[tok][f] * hv[f][vr]   (hv from global/L2)
    const float* hvb = hv + (size_t)hh * 4096 + tx * 4;
    float rt[4][4] = {};
#pragma unroll 4
    for (int f = 0; f < 64; ++f) {
        float4 q4 = *(float4*)(&BUF[f * 68 + ((ty * 4) ^ ((f & 7) << 3))]);
        float4 h4 = *(const float4*)(hvb + f * 64);
        float q[4] = {q4.x, q4.y, q4.z, q4.w};
        float hw[4] = {h4.x, h4.y, h4.z, h4.w};
#pragma unroll
        for (int i = 0; i < 4; ++i)
#pragma unroll
            for (int j = 0; j < 4; ++j) rt[i][j] += q[i] * hw[j];
    }
    __syncthreads();   // QS_T reads done -> safe to overwrite with rot
#pragma unroll
    for (int i = 0; i < 4; ++i)
        *(float4*)(&BUF[(ty * 4 + i) * 68 + tx * 4]) =
            make_float4(rt[i][0], rt[i][1], rt[i][2], rt[i][3]);
    __syncthreads();
    // ---- argmax over concat(-rot, rot), first-occurrence tie-break
    {
        const int tok = tid >> 2, rr2 = tid & 3;
        float best = -BUF[tok * 68 + rr2];
        int bj = 0;
        for (int j = 1; j < 16; ++j) {
            float v = BUF[tok * 68 + j * 4 + rr2];
            if (-v > best) { best = -v; bj = j; }
        }
        for (int j = 0; j < 16; ++j) {
            float v = BUF[tok * 68 + j * 4 + rr2];
            if (v > best) { best = v; bj = 16 + j; }
        }
        int m = m0 + tok;
        int b = m >> 11, s = m & 2047;
        loc2[((size_t)(((b << 3) + hh) * 2048 + s)) * 4 + rr2] = bj;
    }
}

// ---------------------------------------------------------------------------
// split-bf16 MFMA GEMM (3-term), gload_lds staging (unchanged from r11).
// ---------------------------------------------------------------------------
__global__ __launch_bounds__(256) void gemm_pk(const unsigned int* __restrict__ Apk,
                                               const unsigned int* __restrict__ BT,
                                               const float* __restrict__ bias,
                                               void* __restrict__ Cout, int mode) {
    __shared__ __align__(16) unsigned int As[64 * 32];
    __shared__ __align__(16) unsigned int Bs[64 * 32];
    const int m0 = blockIdx.x * 64;
    const int n0 = blockIdx.y * 64;
    const int tid = threadIdx.x;
    const int lane = tid & 63, wv = tid >> 6;
    const int lx = lane & 15, hi = lane >> 4;
    const int wbase = tid & ~63;           // wave-uniform qi base (u=0)
    f32x4 acc[4] = {{0.f,0.f,0.f,0.f},{0.f,0.f,0.f,0.f},{0.f,0.f,0.f,0.f},{0.f,0.f,0.f,0.f}};
    for (int k0 = 0; k0 < 512; k0 += 32) {
#pragma unroll
        for (int u = 0; u < 2; ++u) {
            int qi = u * 256 + tid;
            int row = qi >> 3, qd = qi & 7;
            int sq = (qd ^ (row & 7)) << 2;      // pre-swizzled source quad
            gload_lds16(Apk + (size_t)(m0 + row) * 512 + k0 + sq,
                        &As[(u * 256 + wbase) * 4]);
            gload_lds16(BT + (size_t)(n0 + row) * 512 + k0 + sq,
                        &Bs[(u * 256 + wbase) * 4]);
        }
        __syncthreads();
        int arow = wv * 16 + lx;
        uint4 a0 = *(uint4*)(&As[arow * 32 + (((2 * hi) ^ (arow & 7)) << 2)]);
        uint4 a1 = *(uint4*)(&As[arow * 32 + (((2 * hi + 1) ^ (arow & 7)) << 2)]);
        short8 Ah, Al; mkfrag(a0, a1, Ah, Al);
#pragma unroll
        for (int j = 0; j < 4; ++j) {
            int brow = j * 16 + lx;
            uint4 b0 = *(uint4*)(&Bs[brow * 32 + (((2 * hi) ^ (brow & 7)) << 2)]);
            uint4 b1 = *(uint4*)(&Bs[brow * 32 + (((2 * hi + 1) ^ (brow & 7)) << 2)]);
            short8 Bh2, Bl2; mkfrag(b0, b1, Bh2, Bl2);
            acc[j] = __builtin_amdgcn_mfma_f32_16x16x32_bf16(Ah, Bh2, acc[j], 0, 0, 0);
            acc[j] = __builtin_amdgcn_mfma_f32_16x16x32_bf16(Ah, Bl2, acc[j], 0, 0, 0);
            acc[j] = __builtin_amdgcn_mfma_f32_16x16x32_bf16(Al, Bh2, acc[j], 0, 0, 0);
        }
        __syncthreads();
    }
#pragma unroll
    for (int j = 0; j < 4; ++j) {
        int nn = n0 + j * 16 + lx;
        float bs = bias[nn];
#pragma unroll
        for (int reg = 0; reg < 4; ++reg) {
            int m = m0 + wv * 16 + hi * 4 + reg;
            float val = acc[j][reg] + bs;
            if (mode == 0) {
                int b = m >> 11, ss = m & 2047;
                int hh = nn >> 6, f = nn & 63;
                ((unsigned short*)Cout)[((size_t)(((b << 3) + hh) * 2048 + ss)) * 64 + f] =
                    (unsigned short)f2bf(val);
            } else {
                ((float*)Cout)[(size_t)m * 512 + nn] = val;
            }
        }
    }
}

// ---------------------------------------------------------------------------
// Stable counting sort (unchanged): one 1024-thread block per (b,h,r).
// ---------------------------------------------------------------------------
__global__ __launch_bounds__(1024) void sort_kernel(const int* __restrict__ loc2,
                                                    int* __restrict__ st) {
    __shared__ int hist[32][32];
    __shared__ int off[32][32];
    __shared__ int base[32];
    const int gid = blockIdx.x;    // = bh*4 + r
    const int r = gid & 3, bh = gid >> 2;
    const int tid = threadIdx.x;
    const int lane = tid & 63, wvi = tid >> 6;
    const unsigned long long lower_mask =
        (lane == 0) ? 0ull : ((~0ull) >> (64 - lane));

    int myb[2], myrank[2];
#pragma unroll
    for (int si = 0; si < 2; ++si) {
        int seg = wvi * 2 + si;
        int p = seg * 64 + lane;
        int b = loc2[(size_t)(bh * 2048 + p) * 4 + r];
        myb[si] = b;
        myrank[si] = 0;
#pragma unroll 1
        for (int bkt = 0; bkt < 32; ++bkt) {
            unsigned long long m = __ballot(b == bkt);
            if (b == bkt) myrank[si] = __popcll(m & lower_mask);
            if (lane == bkt) hist[seg][bkt] = __popcll(m);
        }
    }
    __syncthreads();
    if (tid < 32) {
        int running = 0;
#pragma unroll 1
        for (int seg = 0; seg < 32; ++seg) {
            off[seg][tid] = running;
            running += hist[seg][tid];
        }
        base[tid] = running;
    }
    __syncthreads();
    if (tid == 0) {
        int acc = 0;
#pragma unroll 1
        for (int b = 0; b < 32; ++b) { int h = base[b]; base[b] = acc; acc += h; }
    }
    __syncthreads();
#pragma unroll
    for (int si = 0; si < 2; ++si) {
        int seg = wvi * 2 + si;
        int p = seg * 64 + lane;
        int b = myb[si];
        st[(size_t)gid * 2048 + base[b] + off[seg][b] + myrank[si]] = p;
    }
}

// ---------------------------------------------------------------------------
// Chunked attention v7: K staged from plane-split qkr rows (256 B/token);
// fragments read DIRECTLY as 16 B granules (no mkfrag/v_perm in QK^T).
// Granule slot swizzle: slot ^ (row&15) -> 2-way-free banks (same as KQUAD).
// ---------------------------------------------------------------------------
#define KSLOT(row, sl) (((row) << 6) + ((((sl) ^ ((row) & 15))) << 2))
#define PBASE 6400

__global__ __launch_bounds__(256, 3) void attn_kernel(const unsigned short* __restrict__ qkr,
                                                      const unsigned short* __restrict__ vpk,
                                                      const float* __restrict__ scaleQ,
                                                      const int* __restrict__ loc2,
                                                      const int* __restrict__ st,
                                                      float* __restrict__ lseg,
                                                      float* __restrict__ vog) {
    __shared__ __align__(16) unsigned int U[12800];  // K (12288) -> V^T + P
    __shared__ float scaleK[WS_];
    __shared__ int Tk[WS_];
    __shared__ int Lp[WS_];

    const int gid = blockIdx.x;
    const int n = gid & 31;
    const int r = (gid >> 5) & 3;
    const int bh = gid >> 7;
    const int tid = threadIdx.x;
    const int sbase = (bh * 4 + r) * 2048;
    const int lane = tid & 63;
    const int wv = tid >> 6;
    const int lx = lane & 15;
    const int hi = lane >> 4;

    if (tid < WS_) {
        int w = tid;
        int chunk = (n + 31 + (w >> 6)) & 31;
        int t = st[(size_t)sbase + chunk * 64 + (w & 63)];
        Tk[w] = t;
        int4 l4 = *(const int4*)(loc2 + (size_t)(bh * 2048 + t) * 4);
        Lp[w] = l4.x | (l4.y << 8) | (l4.z << 16) | (l4.w << 24);
        scaleK[w] = scaleQ[bh * 2048 + t];
    }
    __syncthreads();

    // ---- stage K: 192 rows x 16 granules (16B), swizzled dest
#pragma unroll
    for (int it = 0; it < 12; ++it) {
        int s = it * 256 + tid;
        int row = s >> 4, sl = s & 15;
        uint4 v4 = *(const uint4*)(qkr + ((size_t)(bh * 2048 + Tk[row])) * 128 + sl * 8);
        *(uint4*)(&U[KSLOT(row, sl)]) = v4;
    }
    __syncthreads();

    // ---- QK^T (swapped): S^T[c][q]; fragments = direct granule reads
    const int qw = 64 + wv * 16 + lx;
    short8 Bh[2], Bl[2];
#pragma unroll
    for (int ks = 0; ks < 2; ++ks) {
        Bh[ks] = __builtin_bit_cast(short8, *(uint4*)(&U[KSLOT(qw, ks * 4 + hi)]));
        Bl[ks] = __builtin_bit_cast(short8, *(uint4*)(&U[KSLOT(qw, 8 + ks * 4 + hi)]));
    }
    f32x4 s[12];
    __builtin_amdgcn_s_setprio(1);
#pragma unroll
    for (int ct = 0; ct < 12; ++ct) {
        f32x4 acc = {0.f, 0.f, 0.f, 0.f};
#pragma unroll
        for (int ks = 0; ks < 2; ++ks) {
            int arow = ct * 16 + lx;
            short8 Ah = __builtin_bit_cast(short8, *(uint4*)(&U[KSLOT(arow, ks * 4 + hi)]));
            short8 Al = __builtin_bit_cast(short8, *(uint4*)(&U[KSLOT(arow, 8 + ks * 4 + hi)]));
            acc = __builtin_amdgcn_mfma_f32_16x16x32_bf16(Ah, Bh[ks], acc, 0, 0, 0);
            acc = __builtin_amdgcn_mfma_f32_16x16x32_bf16(Ah, Bl[ks], acc, 0, 0, 0);
            acc = __builtin_amdgcn_mfma_f32_16x16x32_bf16(Al, Bh[ks], acc, 0, 0, 0);
        }
        s[ct] = acc;
    }
    __builtin_amdgcn_s_setprio(0);

    // issue V loads early (hide HBM/L2 latency under softmax)
    uint4 vl0[3], vl1[3];
#pragma unroll
    for (int it = 0; it < 3; ++it) {
        int idx = it * 256 + tid;
        int pr = idx >> 3, oct = idx & 7;
        vl0[it] = *(const uint4*)(vpk + ((size_t)(bh * 2048 + Tk[pr * 2])) * 64 + oct * 8);
        vl1[it] = *(const uint4*)(vpk + ((size_t)(bh * 2048 + Tk[pr * 2 + 1])) * 64 + oct * 8);
    }
    __syncthreads();   // K reads done; U reusable

    // ---- masks + register softmax (lane owns q = qw, 48 c-values)
    const int lq = Lp[qw];
    const unsigned int bmask = 0x80u << (r * 8);
    float mx = -3.0e38f;
#pragma unroll
    for (int ct = 0; ct < 12; ++ct) {
#pragma unroll
        for (int rr = 0; rr < 4; ++rr) {
            int c = ct * 16 + hi * 4 + rr;
            float val = s[ct][rr] * scaleK[c];
            unsigned int x = (unsigned int)(lq ^ Lp[c]);
            unsigned int z = ((x & 0x7f7f7f7fu) + 0x7f7f7f7fu) | x;
            unsigned int zm = ~z & 0x80808080u;
            int dup = __popc(zm);
            val = (c == qw) ? -100000.0f : val;
            val = (zm & bmask) ? val : NEGF;
            float ld = (dup < 2) ? 0.0f
                     : (dup == 2) ? 0.69314718f
                     : (dup == 3) ? 1.09861229f : 1.38629436f;
            val -= ld;
            s[ct][rr] = val;
            mx = fmaxf(mx, val);
        }
    }
    mx = fmaxf(mx, __shfl_xor(mx, 16));
    mx = fmaxf(mx, __shfl_xor(mx, 32));
    float ssum = 0.f;
#pragma unroll
    for (int ct = 0; ct < 12; ++ct)
#pragma unroll
        for (int rr = 0; rr < 4; ++rr) {
            float e = __expf(s[ct][rr] - mx);
            s[ct][rr] = e;
            ssum += e;
        }
    ssum += __shfl_xor(ssum, 16);
    ssum += __shfl_xor(ssum, 32);
    float lse = mx + __logf(ssum);
    if (hi == 0) lseg[(size_t)sbase + Tk[qw]] = lse;
    float inv = 1.0f / ssum;

    // ---- stage V^T bf16 into U[0..6400): word = f*100 + quad<<2 + w,
    //      quad = (c0>>3) ^ (f&7) ^ (f>>3); interleave via v_perm
#pragma unroll
    for (int it = 0; it < 3; ++it) {
        int idx = it * 256 + tid;
        int pr = idx >> 3, oct = idx & 7;
        int c0 = pr * 2;
        unsigned int aw[4] = {vl0[it].x, vl0[it].y, vl0[it].z, vl0[it].w};
        unsigned int bw[4] = {vl1[it].x, vl1[it].y, vl1[it].z, vl1[it].w};
#pragma unroll
        for (int j = 0; j < 8; ++j) {
            int f = oct * 8 + j;
            unsigned int w2 = (j & 1)
                ? __builtin_amdgcn_perm(bw[j >> 1], aw[j >> 1], 0x07060302u)
                : __builtin_amdgcn_perm(bw[j >> 1], aw[j >> 1], 0x05040100u);
            int quad = (c0 >> 3) ^ (f & 7) ^ (f >> 3);
            U[f * 100 + (quad << 2) + ((c0 & 7) >> 1)] = w2;
        }
    }
    // ---- P[q][c] bf16 into U[PBASE..): word = q*100 + ((c>>1) ^ ((q&3)<<3))
    const int q = wv * 16 + lx;
    const int pxm = (q & 3) << 3;
#pragma unroll
    for (int ct = 0; ct < 12; ++ct) {
        int po = ct * 8 + hi * 2;
        U[PBASE + q * 100 + ((po + 0) ^ pxm)] = cvtpk(s[ct][0] * inv, s[ct][1] * inv);
        U[PBASE + q * 100 + ((po + 1) ^ pxm)] = cvtpk(s[ct][2] * inv, s[ct][3] * inv);
    }
    __syncthreads();

    // ---- PV: O^T[f][q] = V^T . P^T, single-MFMA bf16
    f32x4 o[4] = {{0.f,0.f,0.f,0.f},{0.f,0.f,0.f,0.f},{0.f,0.f,0.f,0.f},{0.f,0.f,0.f,0.f}};
    const unsigned short* Uh = (const unsigned short*)U;
    __builtin_amdgcn_s_setprio(1);
#pragma unroll
    for (int ks = 0; ks < 6; ++ks) {
        short8 P8 = *(const short8*)(Uh + PBASE * 2 + q * 200 +
                                     (((ks * 16 + hi * 4) ^ pxm) << 1));
#pragma unroll
        for (int ft = 0; ft < 4; ++ft) {
            int f = ft * 16 + lx;
            int quad = (4 * ks + hi) ^ (f & 7) ^ (f >> 3);
            short8 V8 = *(const short8*)(Uh + f * 200 + (quad << 3));
            o[ft] = __builtin_amdgcn_mfma_f32_16x16x32_bf16(V8, P8, o[ft], 0, 0, 0);
        }
    }
    __builtin_amdgcn_s_setprio(0);
    const int tko = Tk[qw];
#pragma unroll
    for (int ft = 0; ft < 4; ++ft) {
        float4 w4 = make_float4(o[ft][0], o[ft][1], o[ft][2], o[ft][3]);
        *(float4*)(vog + ((size_t)sbase + tko) * 64 + ft * 16 + hi * 4) = w4;
    }
}

// ---------------------------------------------------------------------------
// Combine rounds -> packed split att; vectorized x4 (float4/uint4).
// ---------------------------------------------------------------------------
__global__ __launch_bounds__(256) void combine_kernel(const float* __restrict__ vog,
                                                      const float* __restrict__ lseg,
                                                      unsigned int* __restrict__ attpk) {
    const int gid = blockIdx.x * 256 + threadIdx.x;   // 524288 total
    const int kq = gid & 15;          // k-quad
    const int t = (gid >> 4) & 2047;
    const int bh = gid >> 15;
    const int b = bh >> 3, h = bh & 7;
    float l[4];
    float4 vo[4];
#pragma unroll
    for (int r = 0; r < 4; ++r) {
        l[r] = lseg[(size_t)(bh * 4 + r) * 2048 + t];
        vo[r] = *(const float4*)(vog + ((size_t)(bh * 4 + r) * 2048 + t) * 64 + kq * 4);
    }
    float m = fmaxf(fmaxf(l[0], l[1]), fmaxf(l[2], l[3]));
    float ss = expf(l[0] - m) + expf(l[1] - m) + expf(l[2] - m) + expf(l[3] - m);
    float lt = m + logf(ss);
    float o0 = 0.f, o1 = 0.f, o2 = 0.f, o3 = 0.f;
#pragma unroll
    for (int r = 0; r < 4; ++r) {
        float w = expf(l[r] - lt);
        o0 += w * vo[r].x; o1 += w * vo[r].y; o2 += w * vo[r].z; o3 += w * vo[r].w;
    }
    uint4 pk = make_uint4(packsplit(o0), packsplit(o1), packsplit(o2), packsplit(o3));
    *(uint4*)(attpk + ((size_t)(b * 2048 + t)) * 512 + h * 64 + kq * 4) = pk;
}

// ---------------------------------------------------------------------------
extern "C" void kernel_launch(void* const* d_in, const int* in_sizes, int n_in,
                              void* d_out, int out_size, void* d_ws, size_t ws_size,
                              hipStream_t stream) {
    const float* x  = (const float*)d_in[0];
    const float* Wq = (const float*)d_in[1];
    const float* bq = (const float*)d_in[2];
    const float* Wv = (const float*)d_in[3];
    const float* bv = (const float*)d_in[4];
    const float* Wo = (const float*)d_in[5];
    const float* bo = (const float*)d_in[6];
    const float* hv = (const float*)d_in[7];

    unsigned int* W = (unsigned int*)d_ws;
    float*          vog    = (float*)W;                         // [0, 8388608) f32
    unsigned int*   xpk    = W + 2097152;                       // alias - dead after v-gemm
    unsigned short* qkr    = (unsigned short*)(W + 8388608);    // 32768 tokens x 256B
    unsigned short* vpk    = (unsigned short*)(W + 10485760);   // 2097152 ushort
    unsigned int*   attpk  = W + 11534336;                      // 2097152
    float*          scaleQ = (float*)(W + 13631488);            // 32768
    int*            loc2   = (int*)(W + 13664256);              // 131072
    int*            stbuf  = (int*)(W + 13795328);              // 131072
    float*          lseg   = (float*)(W + 13926400);            // 131072
    unsigned int*   wvT    = W + 14057472;                      // 262144
    unsigned int*   woT    = W + 14319616;                      // 262144

    dim3 gg(64, 8), blk(256);
    prep_kernel<<<2688, 256, 0, stream>>>(x, Wq, bq, hv, Wv, Wo,
                                          qkr, scaleQ, loc2, xpk, wvT, woT);
    gemm_pk<<<gg, blk, 0, stream>>>(xpk, wvT, bv, (void*)vpk, 0);
    sort_kernel<<<64, 1024, 0, stream>>>(loc2, stbuf);
    attn_kernel<<<2048, 256, 0, stream>>>(qkr, vpk, scaleQ, loc2, stbuf, lseg, vog);
    combine_kernel<<<2048, 256, 0, stream>>>(vog, lseg, attpk);
    gemm_pk<<<gg, blk, 0, stream>>>(attpk, woT, bo, d_out, 1);
}

// Round 13
// 143.663 us; speedup vs baseline: 1.4774x; 1.0217x over previous
//
#include <hip/hip_runtime.h>
#include <hip/hip_bf16.h>
#include <math.h>

// Problem constants (b=2, s=2048, d=512, h=8, k=64, rounds=4, buckets=32, cs=64)
#define WS_ 192          // 3 * 64 (acn=1 window)
#define NEGF (-3.402823466e+38f)

typedef __attribute__((ext_vector_type(8))) short short8;
typedef __attribute__((ext_vector_type(4))) float f32x4;

static __device__ __forceinline__ unsigned int f2bf(float f) {
    unsigned int u = __float_as_uint(f);
    return (u + 0x7FFFu + ((u >> 16) & 1u)) >> 16;
}
// pack f32 into (hi bf16 | lo bf16<<16), hi+lo ~ exact (rel err ~2^-16)
static __device__ __forceinline__ unsigned int packsplit(float v) {
    unsigned int h = f2bf(v);
    float hf = __uint_as_float(h << 16);
    unsigned int l = f2bf(v - hf);
    return h | (l << 16);
}
static __device__ __forceinline__ unsigned int cvtpk(float lo, float hi) {
    unsigned int d;
    asm("v_cvt_pk_bf16_f32 %0, %1, %2" : "=v"(d) : "v"(lo), "v"(hi));
    return d;
}
// async global -> LDS, 16 B per lane; lds base must be wave-uniform
static __device__ __forceinline__ void gload_lds16(const void* g, void* l) {
    __builtin_amdgcn_global_load_lds(
        (const __attribute__((address_space(1))) void*)g,
        (__attribute__((address_space(3))) void*)l, 16, 0, 0);
}

// ---------------------------------------------------------------------------
// prep kernel = qk GEMM+hash (blocks [0,512)) UNION pack (blocks [512,2688)).
// Pack outputs are PLANE-SPLIT rows: 512-k row = [512 bf16 hi | 512 bf16 lo]
// (2 KB).  qk epilogue writes qkr plane-split 64-k rows (256 B).
// Hash math bit-identical to r5-r12.
// ---------------------------------------------------------------------------
__global__ __launch_bounds__(256) void prep_kernel(const float* __restrict__ A,
                                                   const float* __restrict__ W,
                                                   const float* __restrict__ bias,
                                                   const float* __restrict__ hv,
                                                   const float* __restrict__ Wv,
                                                   const float* __restrict__ Wo,
                                                   unsigned short* __restrict__ qkr,
                                                   float* __restrict__ scaleQ,
                                                   int* __restrict__ loc2,
                                                   unsigned short* __restrict__ xpk,
                                                   unsigned short* __restrict__ wvT,
                                                   unsigned short* __restrict__ woT) {
    __shared__ float BUF[4352];      // qk: As|Ws then QS_T->rot ; pack: T[64][65]
    const int bid = blockIdx.x;
    const int tid = threadIdx.x;

    if (bid >= 512) {
        // ================= pack path =================
        int pb = bid - 512;
        if (pb < 2048) {
            int idx = (pb * 256 + tid) * 4;
            int row = idx >> 9, k = idx & 511;
            float4 v = *(const float4*)(A + idx);   // A == x
            unsigned int h0 = f2bf(v.x), h1 = f2bf(v.y), h2 = f2bf(v.z), h3 = f2bf(v.w);
            unsigned int l0 = f2bf(v.x - __uint_as_float(h0 << 16));
            unsigned int l1 = f2bf(v.y - __uint_as_float(h1 << 16));
            unsigned int l2 = f2bf(v.z - __uint_as_float(h2 << 16));
            unsigned int l3 = f2bf(v.w - __uint_as_float(h3 << 16));
            size_t rb = (size_t)row * 1024 + k;
            *(uint2*)(xpk + rb)       = make_uint2(h0 | (h1 << 16), h2 | (h3 << 16));
            *(uint2*)(xpk + rb + 512) = make_uint2(l0 | (l1 << 16), l2 | (l3 << 16));
            return;
        }
        unsigned int* T = (unsigned int*)BUF;       // [64][65] packed u32
        int wb = pb - 2048;                         // 0..127
        const float* Wsrc = (wb < 64) ? Wv : Wo;
        unsigned short* Wdst = (wb < 64) ? wvT : woT;
        int t = wb & 63;
        int k0 = (t >> 3) * 64, n0 = (t & 7) * 64;
#pragma unroll
        for (int pass = 0; pass < 16; ++pass) {
            int i = pass * 4 + (tid >> 6);      // k-offset
            int j = tid & 63;                   // n-offset
            T[j * 65 + i] = packsplit(Wsrc[(size_t)(k0 + i) * 512 + n0 + j]);
        }
        __syncthreads();
#pragma unroll
        for (int pass = 0; pass < 16; ++pass) {
            int j = pass * 4 + (tid >> 6);      // n-offset
            int i = tid & 63;                   // k-offset
            unsigned int pk = T[j * 65 + i];
            size_t rb = (size_t)(n0 + j) * 1024 + k0 + i;
            Wdst[rb]       = (unsigned short)(pk & 0xffffu);
            Wdst[rb + 512] = (unsigned short)(pk >> 16);
        }
        return;
    }

    // ================= qk GEMM + hash path (r7 body) =================
    float* As = BUF;                 // [32][68] k-major
    float* Ws = BUF + 2176;          // [32][68]
    const int m0 = (bid & 63) * 64;
    const int n0 = (bid >> 6) * 64;  // = head * 64
    const int ty = tid >> 4, tx = tid & 15;
    const int ci = tid & 7, ri = tid >> 3;
    const int wk = tid >> 4, wt = tid & 15;
    float acc[4][4] = {};
    for (int k0 = 0; k0 < 512; k0 += 32) {
#pragma unroll
        for (int h2 = 0; h2 < 2; ++h2) {
            int i = ri + h2 * 32;
            float4 a4 = *(const float4*)(A + (size_t)(m0 + i) * 512 + k0 + ci * 4);
            As[(ci * 4 + 0) * 68 + i] = a4.x;
            As[(ci * 4 + 1) * 68 + i] = a4.y;
            As[(ci * 4 + 2) * 68 + i] = a4.z;
            As[(ci * 4 + 3) * 68 + i] = a4.w;
        }
#pragma unroll
        for (int h2 = 0; h2 < 2; ++h2) {
            int kk = wk + h2 * 16;
            float4 w4 = *(const float4*)(W + (size_t)(k0 + kk) * 512 + n0 + wt * 4);
            *(float4*)(&Ws[kk * 68 + wt * 4]) = w4;
        }
        __syncthreads();
#pragma unroll
        for (int kk = 0; kk < 32; ++kk) {
            float4 a4 = *(float4*)(&As[kk * 68 + ty * 4]);
            float4 w4 = *(float4*)(&Ws[kk * 68 + tx * 4]);
            float a[4] = {a4.x, a4.y, a4.z, a4.w};
            float w[4] = {w4.x, w4.y, w4.z, w4.w};
#pragma unroll
            for (int i = 0; i < 4; ++i)
#pragma unroll
                for (int j = 0; j < 4; ++j) acc[i][j] += a[i] * w[j];
        }
        __syncthreads();
    }
    // ---- epilogue: bias, qkr (plane-split), scaleQ
    const int hh = n0 >> 6;
#pragma unroll
    for (int i = 0; i < 4; ++i) {
        int m = m0 + ty * 4 + i;
        int b = m >> 11, s = m & 2047;
        float v0 = acc[i][0] + bias[n0 + tx * 4 + 0];
        float v1 = acc[i][1] + bias[n0 + tx * 4 + 1];
        float v2 = acc[i][2] + bias[n0 + tx * 4 + 2];
        float v3 = acc[i][3] + bias[n0 + tx * 4 + 3];
        acc[i][0] = v0; acc[i][1] = v1; acc[i][2] = v2; acc[i][3] = v3;
        unsigned int h0 = f2bf(v0), h1 = f2bf(v1), h2v = f2bf(v2), h3 = f2bf(v3);
        unsigned int l0 = f2bf(v0 - __uint_as_float(h0 << 16));
        unsigned int l1 = f2bf(v1 - __uint_as_float(h1 << 16));
        unsigned int l2 = f2bf(v2 - __uint_as_float(h2v << 16));
        unsigned int l3 = f2bf(v3 - __uint_as_float(h3 << 16));
        size_t trow = ((size_t)(((b << 3) + hh) * 2048 + s)) * 128;
        *(uint2*)(qkr + trow + tx * 4) =
            make_uint2(h0 | (h1 << 16), h2v | (h3 << 16));
        *(uint2*)(qkr + trow + 64 + tx * 4) =
            make_uint2(l0 | (l1 << 16), l2 | (l3 << 16));
        float sq = v0 * v0 + v1 * v1 + v2 * v2 + v3 * v3;
        sq += __shfl_xor(sq, 1, 16); sq += __shfl_xor(sq, 2, 16);
        sq += __shfl_xor(sq, 4, 16); sq += __shfl_xor(sq, 8, 16);
        if (tx == 0)
            scaleQ[(size_t)(((b << 3) + hh) * 2048 + s)] = 0.125f / fmaxf(sqrtf(sq), 1e-12f);
    }
    // ---- write qk^T to LDS: QS_T[f][tok ^ ((f&7)<<3)]
#pragma unroll
    for (int j = 0; j < 4; ++j) {
        int f = tx * 4 + j;
        int xm = (f & 7) << 3;
#pragma unroll
        for (int i = 0; i < 4; ++i)
            BUF[f * 68 + ((ty * 4 + i) ^ xm)] = acc[i][j];
    }
    __syncthreads();
    // ---- rot[tok][vr] = sum_f qk[tok][f] * hv[f][vr]   (hv from global/L2)
    const float* hvb = hv + (size_t)hh * 4096 + tx * 4;
    float rt[4][4] = {};
#pragma unroll 4
    for (int f = 0; f < 64; ++f) {
        float4 q4 = *(float4*)(&BUF[f * 68 + ((ty * 4) ^ ((f & 7) << 3))]);
        float4 h4 = *(const float4*)(hvb + f * 64);
        float q[4] = {q4.x, q4.y, q4.z, q4.w};
        float hw[4] = {h4.x, h4.y, h4.z, h4.w};
#pragma unroll
        for (int i = 0; i < 4; ++i)
#pragma unroll
            for (int j = 0; j < 4; ++j) rt[i][j] += q[i] * hw[j];
    }
    __syncthreads();   // QS_T reads done -> safe to overwrite with rot
#pragma unroll
    for (int i = 0; i < 4; ++i)
        *(float4*)(&BUF[(ty * 4 + i) * 68 + tx * 4]) =
            make_float4(rt[i][0], rt[i][1], rt[i][2], rt[i][3]);
    __syncthreads();
    // ---- argmax over concat(-rot, rot), first-occurrence tie-break
    {
        const int tok = tid >> 2, rr2 = tid & 3;
        float best = -BUF[tok * 68 + rr2];
        int bj = 0;
        for (int j = 1; j < 16; ++j) {
            float v = BUF[tok * 68 + j * 4 + rr2];
            if (-v > best) { best = -v; bj = j; }
        }
        for (int j = 0; j < 16; ++j) {
            float v = BUF[tok * 68 + j * 4 + rr2];
            if (v > best) { best = v; bj = 16 + j; }
        }
        int m = m0 + tok;
        int b = m >> 11, s = m & 2047;
        loc2[((size_t)(((b << 3) + hh) * 2048 + s)) * 4 + rr2] = bj;
    }
}

// ---------------------------------------------------------------------------
// split-bf16 MFMA GEMM (3-term), plane-split operands: fragments are direct
// 16B granule reads (no mkfrag).  gload_lds staging, source-side XOR swizzle
// slot^(row&7).  Blocks [512,576) in mode 0 run the counting sort (4 waves
// x 8 segments) so it overlaps the v-projection GEMM.
// mode 0: write bf16 to (b,h,s,k) layout (v path); mode 1: f32 row-major.
// ---------------------------------------------------------------------------
__global__ __launch_bounds__(256) void gemm_pk(const unsigned short* __restrict__ Apk,
                                               const unsigned short* __restrict__ BT,
                                               const float* __restrict__ bias,
                                               void* __restrict__ Cout, int mode,
                                               const int* __restrict__ loc2,
                                               int* __restrict__ st) {
    __shared__ __align__(16) unsigned int As[64 * 32];
    __shared__ __align__(16) unsigned int Bs[64 * 32];
    const int bid = blockIdx.x;
    const int tid = threadIdx.x;

    if (bid >= 512) {
        // ================= counting sort path (overlaps v-GEMM) ============
        int gid = bid - 512;                  // = bh*4 + r
        int r = gid & 3, bh = gid >> 2;
        int* hist = (int*)As;                 // [32][32]
        int* off  = (int*)As + 1024;          // [32][32]
        int* base = (int*)Bs;                 // [32]
        const int lane = tid & 63, wvi = tid >> 6;
        const unsigned long long lower_mask =
            (lane == 0) ? 0ull : ((~0ull) >> (64 - lane));
        int myb[8], myrank[8];
#pragma unroll
        for (int si = 0; si < 8; ++si) {
            int seg = wvi * 8 + si;
            int p = seg * 64 + lane;
            int b = loc2[(size_t)(bh * 2048 + p) * 4 + r];
            myb[si] = b;
            myrank[si] = 0;
#pragma unroll 1
            for (int bkt = 0; bkt < 32; ++bkt) {
                unsigned long long m = __ballot(b == bkt);
                if (b == bkt) myrank[si] = __popcll(m & lower_mask);
                if (lane == bkt) hist[seg * 32 + bkt] = __popcll(m);
            }
        }
        __syncthreads();
        if (tid < 32) {
            int running = 0;
#pragma unroll 1
            for (int seg = 0; seg < 32; ++seg) {
                off[seg * 32 + tid] = running;
                running += hist[seg * 32 + tid];
            }
            base[tid] = running;
        }
        __syncthreads();
        if (tid == 0) {
            int a2 = 0;
#pragma unroll 1
            for (int b = 0; b < 32; ++b) { int h = base[b]; base[b] = a2; a2 += h; }
        }
        __syncthreads();
#pragma unroll
        for (int si = 0; si < 8; ++si) {
            int seg = wvi * 8 + si;
            int p = seg * 64 + lane;
            int b = myb[si];
            st[(size_t)gid * 2048 + base[b] + off[seg * 32 + b] + myrank[si]] = p;
        }
        return;
    }

    // ================= GEMM path =================
    const int m0 = (bid & 63) * 64;
    const int n0 = (bid >> 6) * 64;
    const int lane = tid & 63, wv = tid >> 6;
    const int lx = lane & 15, fg = lane >> 4;
    const int wbase = tid & ~63;           // wave-uniform qi base (u=0)
    f32x4 acc[4] = {{0.f,0.f,0.f,0.f},{0.f,0.f,0.f,0.f},{0.f,0.f,0.f,0.f},{0.f,0.f,0.f,0.f}};
    for (int k0 = 0; k0 < 512; k0 += 32) {
#pragma unroll
        for (int u = 0; u < 2; ++u) {
            int qi = u * 256 + tid;
            int row = qi >> 3, sl = qi & 7;
            int ssl = sl ^ (row & 7);              // pre-swizzled source slot
            int offp = (ssl < 4) ? (k0 + ssl * 8) : (512 + k0 + (ssl - 4) * 8);
            gload_lds16(Apk + (size_t)(m0 + row) * 1024 + offp,
                        &As[(u * 256 + wbase) * 4]);
            gload_lds16(BT + (size_t)(n0 + row) * 1024 + offp,
                        &Bs[(u * 256 + wbase) * 4]);
        }
        __syncthreads();
        int arow = wv * 16 + lx;
        short8 Ah = __builtin_bit_cast(short8,
            *(uint4*)(&As[arow * 32 + ((fg ^ (arow & 7)) << 2)]));
        short8 Al = __builtin_bit_cast(short8,
            *(uint4*)(&As[arow * 32 + (((4 + fg) ^ (arow & 7)) << 2)]));
#pragma unroll
        for (int j = 0; j < 4; ++j) {
            int brow = j * 16 + lx;
            short8 Bh2 = __builtin_bit_cast(short8,
                *(uint4*)(&Bs[brow * 32 + ((fg ^ (brow & 7)) << 2)]));
            short8 Bl2 = __builtin_bit_cast(short8,
                *(uint4*)(&Bs[brow * 32 + (((4 + fg) ^ (brow & 7)) << 2)]));
            acc[j] = __builtin_amdgcn_mfma_f32_16x16x32_bf16(Ah, Bh2, acc[j], 0, 0, 0);
            acc[j] = __builtin_amdgcn_mfma_f32_16x16x32_bf16(Ah, Bl2, acc[j], 0, 0, 0);
            acc[j] = __builtin_amdgcn_mfma_f32_16x16x32_bf16(Al, Bh2, acc[j], 0, 0, 0);
        }
        __syncthreads();
    }
#pragma unroll
    for (int j = 0; j < 4; ++j) {
        int nn = n0 + j * 16 + lx;
        float bs = bias[nn];
#pragma unroll
        for (int reg = 0; reg < 4; ++reg) {
            int m = m0 + wv * 16 + fg * 4 + reg;
            float val = acc[j][reg] + bs;
            if (mode == 0) {
                int b = m >> 11, ss = m & 2047;
                int hh = nn >> 6, f = nn & 63;
                ((unsigned short*)Cout)[((size_t)(((b << 3) + hh) * 2048 + ss)) * 64 + f] =
                    (unsigned short)f2bf(val);
            } else {
                ((float*)Cout)[(size_t)m * 512 + nn] = val;
            }
        }
    }
}

// ---------------------------------------------------------------------------
// Chunked attention v7 (unchanged from round 12).
// ---------------------------------------------------------------------------
#define KSLOT(row, sl) (((row) << 6) + ((((sl) ^ ((row) & 15))) << 2))
#define PBASE 6400

__global__ __launch_bounds__(256, 3) void attn_kernel(const unsigned short* __restrict__ qkr,
                                                      const unsigned short* __restrict__ vpk,
                                                      const float* __restrict__ scaleQ,
                                                      const int* __restrict__ loc2,
                                                      const int* __restrict__ st,
                                                      float* __restrict__ lseg,
                                                      float* __restrict__ vog) {
    __shared__ __align__(16) unsigned int U[12800];  // K (12288) -> V^T + P
    __shared__ float scaleK[WS_];
    __shared__ int Tk[WS_];
    __shared__ int Lp[WS_];

    const int gid = blockIdx.x;
    const int n = gid & 31;
    const int r = (gid >> 5) & 3;
    const int bh = gid >> 7;
    const int tid = threadIdx.x;
    const int sbase = (bh * 4 + r) * 2048;
    const int lane = tid & 63;
    const int wv = tid >> 6;
    const int lx = lane & 15;
    const int hi = lane >> 4;

    if (tid < WS_) {
        int w = tid;
        int chunk = (n + 31 + (w >> 6)) & 31;
        int t = st[(size_t)sbase + chunk * 64 + (w & 63)];
        Tk[w] = t;
        int4 l4 = *(const int4*)(loc2 + (size_t)(bh * 2048 + t) * 4);
        Lp[w] = l4.x | (l4.y << 8) | (l4.z << 16) | (l4.w << 24);
        scaleK[w] = scaleQ[bh * 2048 + t];
    }
    __syncthreads();

    // ---- stage K: 192 rows x 16 granules (16B), swizzled dest
#pragma unroll
    for (int it = 0; it < 12; ++it) {
        int s = it * 256 + tid;
        int row = s >> 4, sl = s & 15;
        uint4 v4 = *(const uint4*)(qkr + ((size_t)(bh * 2048 + Tk[row])) * 128 + sl * 8);
        *(uint4*)(&U[KSLOT(row, sl)]) = v4;
    }
    __syncthreads();

    // ---- QK^T (swapped): S^T[c][q]; fragments = direct granule reads
    const int qw = 64 + wv * 16 + lx;
    short8 Bh[2], Bl[2];
#pragma unroll
    for (int ks = 0; ks < 2; ++ks) {
        Bh[ks] = __builtin_bit_cast(short8, *(uint4*)(&U[KSLOT(qw, ks * 4 + hi)]));
        Bl[ks] = __builtin_bit_cast(short8, *(uint4*)(&U[KSLOT(qw, 8 + ks * 4 + hi)]));
    }
    f32x4 s[12];
    __builtin_amdgcn_s_setprio(1);
#pragma unroll
    for (int ct = 0; ct < 12; ++ct) {
        f32x4 acc = {0.f, 0.f, 0.f, 0.f};
#pragma unroll
        for (int ks = 0; ks < 2; ++ks) {
            int arow = ct * 16 + lx;
            short8 Ah = __builtin_bit_cast(short8, *(uint4*)(&U[KSLOT(arow, ks * 4 + hi)]));
            short8 Al = __builtin_bit_cast(short8, *(uint4*)(&U[KSLOT(arow, 8 + ks * 4 + hi)]));
            acc = __builtin_amdgcn_mfma_f32_16x16x32_bf16(Ah, Bh[ks], acc, 0, 0, 0);
            acc = __builtin_amdgcn_mfma_f32_16x16x32_bf16(Ah, Bl[ks], acc, 0, 0, 0);
            acc = __builtin_amdgcn_mfma_f32_16x16x32_bf16(Al, Bh[ks], acc, 0, 0, 0);
        }
        s[ct] = acc;
    }
    __builtin_amdgcn_s_setprio(0);

    // issue V loads early (hide HBM/L2 latency under softmax)
    uint4 vl0[3], vl1[3];
#pragma unroll
    for (int it = 0; it < 3; ++it) {
        int idx = it * 256 + tid;
        int pr = idx >> 3, oct = idx & 7;
        vl0[it] = *(const uint4*)(vpk + ((size_t)(bh * 2048 + Tk[pr * 2])) * 64 + oct * 8);
        vl1[it] = *(const uint4*)(vpk + ((size_t)(bh * 2048 + Tk[pr * 2 + 1])) * 64 + oct * 8);
    }
    __syncthreads();   // K reads done; U reusable

    // ---- masks + register softmax (lane owns q = qw, 48 c-values)
    const int lq = Lp[qw];
    const unsigned int bmask = 0x80u << (r * 8);
    float mx = -3.0e38f;
#pragma unroll
    for (int ct = 0; ct < 12; ++ct) {
#pragma unroll
        for (int rr = 0; rr < 4; ++rr) {
            int c = ct * 16 + hi * 4 + rr;
            float val = s[ct][rr] * scaleK[c];
            unsigned int x = (unsigned int)(lq ^ Lp[c]);
            unsigned int z = ((x & 0x7f7f7f7fu) + 0x7f7f7f7fu) | x;
            unsigned int zm = ~z & 0x80808080u;
            int dup = __popc(zm);
            val = (c == qw) ? -100000.0f : val;
            val = (zm & bmask) ? val : NEGF;
            float ld = (dup < 2) ? 0.0f
                     : (dup == 2) ? 0.69314718f
                     : (dup == 3) ? 1.09861229f : 1.38629436f;
            val -= ld;
            s[ct][rr] = val;
            mx = fmaxf(mx, val);
        }
    }
    mx = fmaxf(mx, __shfl_xor(mx, 16));
    mx = fmaxf(mx, __shfl_xor(mx, 32));
    float ssum = 0.f;
#pragma unroll
    for (int ct = 0; ct < 12; ++ct)
#pragma unroll
        for (int rr = 0; rr < 4; ++rr) {
            float e = __expf(s[ct][rr] - mx);
            s[ct][rr] = e;
            ssum += e;
        }
    ssum += __shfl_xor(ssum, 16);
    ssum += __shfl_xor(ssum, 32);
    float lse = mx + __logf(ssum);
    if (hi == 0) lseg[(size_t)sbase + Tk[qw]] = lse;
    float inv = 1.0f / ssum;

    // ---- stage V^T bf16 into U[0..6400): word = f*100 + quad<<2 + w,
    //      quad = (c0>>3) ^ (f&7) ^ (f>>3); interleave via v_perm
#pragma unroll
    for (int it = 0; it < 3; ++it) {
        int idx = it * 256 + tid;
        int pr = idx >> 3, oct = idx & 7;
        int c0 = pr * 2;
        unsigned int aw[4] = {vl0[it].x, vl0[it].y, vl0[it].z, vl0[it].w};
        unsigned int bw[4] = {vl1[it].x, vl1[it].y, vl1[it].z, vl1[it].w};
#pragma unroll
        for (int j = 0; j < 8; ++j) {
            int f = oct * 8 + j;
            unsigned int w2 = (j & 1)
                ? __builtin_amdgcn_perm(bw[j >> 1], aw[j >> 1], 0x07060302u)
                : __builtin_amdgcn_perm(bw[j >> 1], aw[j >> 1], 0x05040100u);
            int quad = (c0 >> 3) ^ (f & 7) ^ (f >> 3);
            U[f * 100 + (quad << 2) + ((c0 & 7) >> 1)] = w2;
        }
    }
    // ---- P[q][c] bf16 into U[PBASE..): word = q*100 + ((c>>1) ^ ((q&3)<<3))
    const int q = wv * 16 + lx;
    const int pxm = (q & 3) << 3;
#pragma unroll
    for (int ct = 0; ct < 12; ++ct) {
        int po = ct * 8 + hi * 2;
        U[PBASE + q * 100 + ((po + 0) ^ pxm)] = cvtpk(s[ct][0] * inv, s[ct][1] * inv);
        U[PBASE + q * 100 + ((po + 1) ^ pxm)] = cvtpk(s[ct][2] * inv, s[ct][3] * inv);
    }
    __syncthreads();

    // ---- PV: O^T[f][q] = V^T . P^T, single-MFMA bf16
    f32x4 o[4] = {{0.f,0.f,0.f,0.f},{0.f,0.f,0.f,0.f},{0.f,0.f,0.f,0.f},{0.f,0.f,0.f,0.f}};
    const unsigned short* Uh = (const unsigned short*)U;
    __builtin_amdgcn_s_setprio(1);
#pragma unroll
    for (int ks = 0; ks < 6; ++ks) {
        short8 P8 = *(const short8*)(Uh + PBASE * 2 + q * 200 +
                                     (((ks * 16 + hi * 4) ^ pxm) << 1));
#pragma unroll
        for (int ft = 0; ft < 4; ++ft) {
            int f = ft * 16 + lx;
            int quad = (4 * ks + hi) ^ (f & 7) ^ (f >> 3);
            short8 V8 = *(const short8*)(Uh + f * 200 + (quad << 3));
            o[ft] = __builtin_amdgcn_mfma_f32_16x16x32_bf16(V8, P8, o[ft], 0, 0, 0);
        }
    }
    __builtin_amdgcn_s_setprio(0);
    const int tko = Tk[qw];
#pragma unroll
    for (int ft = 0; ft < 4; ++ft) {
        float4 w4 = make_float4(o[ft][0], o[ft][1], o[ft][2], o[ft][3]);
        *(float4*)(vog + ((size_t)sbase + tko) * 64 + ft * 16 + hi * 4) = w4;
    }
}

// ---------------------------------------------------------------------------
// Combine rounds -> PLANE-SPLIT att rows (A of the Wo GEMM); vectorized x4.
// ---------------------------------------------------------------------------
__global__ __launch_bounds__(256) void combine_kernel(const float* __restrict__ vog,
                                                      const float* __restrict__ lseg,
                                                      unsigned short* __restrict__ attpk) {
    const int gid = blockIdx.x * 256 + threadIdx.x;   // 524288 total
    const int kq = gid & 15;          // k-quad
    const int t = (gid >> 4) & 2047;
    const int bh = gid >> 15;
    const int b = bh >> 3, h = bh & 7;
    float l[4];
    float4 vo[4];
#pragma unroll
    for (int r = 0; r < 4; ++r) {
        l[r] = lseg[(size_t)(bh * 4 + r) * 2048 + t];
        vo[r] = *(const float4*)(vog + ((size_t)(bh * 4 + r) * 2048 + t) * 64 + kq * 4);
    }
    float m = fmaxf(fmaxf(l[0], l[1]), fmaxf(l[2], l[3]));
    float ss = expf(l[0] - m) + expf(l[1] - m) + expf(l[2] - m) + expf(l[3] - m);
    float lt = m + logf(ss);
    float o0 = 0.f, o1 = 0.f, o2 = 0.f, o3 = 0.f;
#pragma unroll
    for (int r = 0; r < 4; ++r) {
        float w = expf(l[r] - lt);
        o0 += w * vo[r].x; o1 += w * vo[r].y; o2 += w * vo[r].z; o3 += w * vo[r].w;
    }
    unsigned int h0 = f2bf(o0), h1 = f2bf(o1), h2 = f2bf(o2), h3 = f2bf(o3);
    unsigned int l0 = f2bf(o0 - __uint_as_float(h0 << 16));
    unsigned int l1 = f2bf(o1 - __uint_as_float(h1 << 16));
    unsigned int l2 = f2bf(o2 - __uint_as_float(h2 << 16));
    unsigned int l3 = f2bf(o3 - __uint_as_float(h3 << 16));
    size_t rb = ((size_t)(b * 2048 + t)) * 1024 + h * 64 + kq * 4;
    *(uint2*)(attpk + rb)       = make_uint2(h0 | (h1 << 16), h2 | (h3 << 16));
    *(uint2*)(attpk + rb + 512) = make_uint2(l0 | (l1 << 16), l2 | (l3 << 16));
}

// ---------------------------------------------------------------------------
extern "C" void kernel_launch(void* const* d_in, const int* in_sizes, int n_in,
                              void* d_out, int out_size, void* d_ws, size_t ws_size,
                              hipStream_t stream) {
    const float* x  = (const float*)d_in[0];
    const float* Wq = (const float*)d_in[1];
    const float* bq = (const float*)d_in[2];
    const float* Wv = (const float*)d_in[3];
    const float* bv = (const float*)d_in[4];
    const float* Wo = (const float*)d_in[5];
    const float* bo = (const float*)d_in[6];
    const float* hv = (const float*)d_in[7];

    unsigned int* W = (unsigned int*)d_ws;
    float*          vog    = (float*)W;                         // [0, 8388608) f32
    unsigned short* xpk    = (unsigned short*)(W + 2097152);    // alias - dead after v-gemm
    unsigned short* qkr    = (unsigned short*)(W + 8388608);    // 32768 tokens x 256B
    unsigned short* vpk    = (unsigned short*)(W + 10485760);   // 2097152 ushort
    unsigned short* attpk  = (unsigned short*)(W + 11534336);   // 4096 rows x 2KB
    float*          scaleQ = (float*)(W + 13631488);            // 32768
    int*            loc2   = (int*)(W + 13664256);              // 131072
    int*            stbuf  = (int*)(W + 13795328);              // 131072
    float*          lseg   = (float*)(W + 13926400);            // 131072
    unsigned short* wvT    = (unsigned short*)(W + 14057472);   // 512 rows x 2KB
    unsigned short* woT    = (unsigned short*)(W + 14319616);   // 512 rows x 2KB

    dim3 blk(256);
    prep_kernel<<<2688, blk, 0, stream>>>(x, Wq, bq, hv, Wv, Wo,
                                          qkr, scaleQ, loc2, xpk, wvT, woT);
    gemm_pk<<<576, blk, 0, stream>>>(xpk, wvT, bv, (void*)vpk, 0, loc2, stbuf);
    attn_kernel<<<2048, blk, 0, stream>>>(qkr, vpk, scaleQ, loc2, stbuf, lseg, vog);
    combine_kernel<<<2048, blk, 0, stream>>>(vog, lseg, attpk);
    gemm_pk<<<512, blk, 0, stream>>>(attpk, woT, bo, d_out, 1, loc2, stbuf);
}

// Round 14
// 139.708 us; speedup vs baseline: 1.5192x; 1.0283x over previous
//
#include <hip/hip_runtime.h>
#include <hip/hip_bf16.h>
#include <hip/hip_fp16.h>
#include <math.h>

// Problem constants (b=2, s=2048, d=512, h=8, k=64, rounds=4, buckets=32, cs=64)
#define WS_ 192          // 3 * 64 (acn=1 window)
#define NEGF (-3.402823466e+38f)

typedef __attribute__((ext_vector_type(8))) short short8;
typedef __attribute__((ext_vector_type(4))) float f32x4;

static __device__ __forceinline__ unsigned int f2bf(float f) {
    unsigned int u = __float_as_uint(f);
    return (u + 0x7FFFu + ((u >> 16) & 1u)) >> 16;
}
// pack f32 into (hi bf16 | lo bf16<<16), hi+lo ~ exact (rel err ~2^-16)
static __device__ __forceinline__ unsigned int packsplit(float v) {
    unsigned int h = f2bf(v);
    float hf = __uint_as_float(h << 16);
    unsigned int l = f2bf(v - hf);
    return h | (l << 16);
}
static __device__ __forceinline__ unsigned int cvtpk(float lo, float hi) {
    unsigned int d;
    asm("v_cvt_pk_bf16_f32 %0, %1, %2" : "=v"(d) : "v"(lo), "v"(hi));
    return d;
}
// async global -> LDS, 16 B per lane; lds base must be wave-uniform
static __device__ __forceinline__ void gload_lds16(const void* g, void* l) {
    __builtin_amdgcn_global_load_lds(
        (const __attribute__((address_space(1))) void*)g,
        (__attribute__((address_space(3))) void*)l, 16, 0, 0);
}

// ---------------------------------------------------------------------------
// prep kernel = qk GEMM+hash (blocks [0,512)) UNION pack (blocks [512,2688)).
// (unchanged from round 13)
// ---------------------------------------------------------------------------
__global__ __launch_bounds__(256) void prep_kernel(const float* __restrict__ A,
                                                   const float* __restrict__ W,
                                                   const float* __restrict__ bias,
                                                   const float* __restrict__ hv,
                                                   const float* __restrict__ Wv,
                                                   const float* __restrict__ Wo,
                                                   unsigned short* __restrict__ qkr,
                                                   float* __restrict__ scaleQ,
                                                   int* __restrict__ loc2,
                                                   unsigned short* __restrict__ xpk,
                                                   unsigned short* __restrict__ wvT,
                                                   unsigned short* __restrict__ woT) {
    __shared__ float BUF[4352];      // qk: As|Ws then QS_T->rot ; pack: T[64][65]
    const int bid = blockIdx.x;
    const int tid = threadIdx.x;

    if (bid >= 512) {
        // ================= pack path =================
        int pb = bid - 512;
        if (pb < 2048) {
            int idx = (pb * 256 + tid) * 4;
            int row = idx >> 9, k = idx & 511;
            float4 v = *(const float4*)(A + idx);   // A == x
            unsigned int h0 = f2bf(v.x), h1 = f2bf(v.y), h2 = f2bf(v.z), h3 = f2bf(v.w);
            unsigned int l0 = f2bf(v.x - __uint_as_float(h0 << 16));
            unsigned int l1 = f2bf(v.y - __uint_as_float(h1 << 16));
            unsigned int l2 = f2bf(v.z - __uint_as_float(h2 << 16));
            unsigned int l3 = f2bf(v.w - __uint_as_float(h3 << 16));
            size_t rb = (size_t)row * 1024 + k;
            *(uint2*)(xpk + rb)       = make_uint2(h0 | (h1 << 16), h2 | (h3 << 16));
            *(uint2*)(xpk + rb + 512) = make_uint2(l0 | (l1 << 16), l2 | (l3 << 16));
            return;
        }
        unsigned int* T = (unsigned int*)BUF;       // [64][65] packed u32
        int wb = pb - 2048;                         // 0..127
        const float* Wsrc = (wb < 64) ? Wv : Wo;
        unsigned short* Wdst = (wb < 64) ? wvT : woT;
        int t = wb & 63;
        int k0 = (t >> 3) * 64, n0 = (t & 7) * 64;
#pragma unroll
        for (int pass = 0; pass < 16; ++pass) {
            int i = pass * 4 + (tid >> 6);      // k-offset
            int j = tid & 63;                   // n-offset
            T[j * 65 + i] = packsplit(Wsrc[(size_t)(k0 + i) * 512 + n0 + j]);
        }
        __syncthreads();
#pragma unroll
        for (int pass = 0; pass < 16; ++pass) {
            int j = pass * 4 + (tid >> 6);      // n-offset
            int i = tid & 63;                   // k-offset
            unsigned int pk = T[j * 65 + i];
            size_t rb = (size_t)(n0 + j) * 1024 + k0 + i;
            Wdst[rb]       = (unsigned short)(pk & 0xffffu);
            Wdst[rb + 512] = (unsigned short)(pk >> 16);
        }
        return;
    }

    // ================= qk GEMM + hash path (r7 body) =================
    float* As = BUF;                 // [32][68] k-major
    float* Ws = BUF + 2176;          // [32][68]
    const int m0 = (bid & 63) * 64;
    const int n0 = (bid >> 6) * 64;  // = head * 64
    const int ty = tid >> 4, tx = tid & 15;
    const int ci = tid & 7, ri = tid >> 3;
    const int wk = tid >> 4, wt = tid & 15;
    float acc[4][4] = {};
    for (int k0 = 0; k0 < 512; k0 += 32) {
#pragma unroll
        for (int h2 = 0; h2 < 2; ++h2) {
            int i = ri + h2 * 32;
            float4 a4 = *(const float4*)(A + (size_t)(m0 + i) * 512 + k0 + ci * 4);
            As[(ci * 4 + 0) * 68 + i] = a4.x;
            As[(ci * 4 + 1) * 68 + i] = a4.y;
            As[(ci * 4 + 2) * 68 + i] = a4.z;
            As[(ci * 4 + 3) * 68 + i] = a4.w;
        }
#pragma unroll
        for (int h2 = 0; h2 < 2; ++h2) {
            int kk = wk + h2 * 16;
            float4 w4 = *(const float4*)(W + (size_t)(k0 + kk) * 512 + n0 + wt * 4);
            *(float4*)(&Ws[kk * 68 + wt * 4]) = w4;
        }
        __syncthreads();
#pragma unroll
        for (int kk = 0; kk < 32; ++kk) {
            float4 a4 = *(float4*)(&As[kk * 68 + ty * 4]);
            float4 w4 = *(float4*)(&Ws[kk * 68 + tx * 4]);
            float a[4] = {a4.x, a4.y, a4.z, a4.w};
            float w[4] = {w4.x, w4.y, w4.z, w4.w};
#pragma unroll
            for (int i = 0; i < 4; ++i)
#pragma unroll
                for (int j = 0; j < 4; ++j) acc[i][j] += a[i] * w[j];
        }
        __syncthreads();
    }
    // ---- epilogue: bias, qkr (plane-split), scaleQ
    const int hh = n0 >> 6;
#pragma unroll
    for (int i = 0; i < 4; ++i) {
        int m = m0 + ty * 4 + i;
        int b = m >> 11, s = m & 2047;
        float v0 = acc[i][0] + bias[n0 + tx * 4 + 0];
        float v1 = acc[i][1] + bias[n0 + tx * 4 + 1];
        float v2 = acc[i][2] + bias[n0 + tx * 4 + 2];
        float v3 = acc[i][3] + bias[n0 + tx * 4 + 3];
        acc[i][0] = v0; acc[i][1] = v1; acc[i][2] = v2; acc[i][3] = v3;
        unsigned int h0 = f2bf(v0), h1 = f2bf(v1), h2v = f2bf(v2), h3 = f2bf(v3);
        unsigned int l0 = f2bf(v0 - __uint_as_float(h0 << 16));
        unsigned int l1 = f2bf(v1 - __uint_as_float(h1 << 16));
        unsigned int l2 = f2bf(v2 - __uint_as_float(h2v << 16));
        unsigned int l3 = f2bf(v3 - __uint_as_float(h3 << 16));
        size_t trow = ((size_t)(((b << 3) + hh) * 2048 + s)) * 128;
        *(uint2*)(qkr + trow + tx * 4) =
            make_uint2(h0 | (h1 << 16), h2v | (h3 << 16));
        *(uint2*)(qkr + trow + 64 + tx * 4) =
            make_uint2(l0 | (l1 << 16), l2 | (l3 << 16));
        float sq = v0 * v0 + v1 * v1 + v2 * v2 + v3 * v3;
        sq += __shfl_xor(sq, 1, 16); sq += __shfl_xor(sq, 2, 16);
        sq += __shfl_xor(sq, 4, 16); sq += __shfl_xor(sq, 8, 16);
        if (tx == 0)
            scaleQ[(size_t)(((b << 3) + hh) * 2048 + s)] = 0.125f / fmaxf(sqrtf(sq), 1e-12f);
    }
    // ---- write qk^T to LDS: QS_T[f][tok ^ ((f&7)<<3)]
#pragma unroll
    for (int j = 0; j < 4; ++j) {
        int f = tx * 4 + j;
        int xm = (f & 7) << 3;
#pragma unroll
        for (int i = 0; i < 4; ++i)
            BUF[f * 68 + ((ty * 4 + i) ^ xm)] = acc[i][j];
    }
    __syncthreads();
    // ---- rot[tok][vr] = sum_f qk[tok][f] * hv[f][vr]   (hv from global/L2)
    const float* hvb = hv + (size_t)hh * 4096 + tx * 4;
    float rt[4][4] = {};
#pragma unroll 4
    for (int f = 0; f < 64; ++f) {
        float4 q4 = *(float4*)(&BUF[f * 68 + ((ty * 4) ^ ((f & 7) << 3))]);
        float4 h4 = *(const float4*)(hvb + f * 64);
        float q[4] = {q4.x, q4.y, q4.z, q4.w};
        float hw[4] = {h4.x, h4.y, h4.z, h4.w};
#pragma unroll
        for (int i = 0; i < 4; ++i)
#pragma unroll
            for (int j = 0; j < 4; ++j) rt[i][j] += q[i] * hw[j];
    }
    __syncthreads();   // QS_T reads done -> safe to overwrite with rot
#pragma unroll
    for (int i = 0; i < 4; ++i)
        *(float4*)(&BUF[(ty * 4 + i) * 68 + tx * 4]) =
            make_float4(rt[i][0], rt[i][1], rt[i][2], rt[i][3]);
    __syncthreads();
    // ---- argmax over concat(-rot, rot), first-occurrence tie-break
    {
        const int tok = tid >> 2, rr2 = tid & 3;
        float best = -BUF[tok * 68 + rr2];
        int bj = 0;
        for (int j = 1; j < 16; ++j) {
            float v = BUF[tok * 68 + j * 4 + rr2];
            if (-v > best) { best = -v; bj = j; }
        }
        for (int j = 0; j < 16; ++j) {
            float v = BUF[tok * 68 + j * 4 + rr2];
            if (v > best) { best = v; bj = 16 + j; }
        }
        int m = m0 + tok;
        int b = m >> 11, s = m & 2047;
        loc2[((size_t)(((b << 3) + hh) * 2048 + s)) * 4 + rr2] = bj;
    }
}

// ---------------------------------------------------------------------------
// split-bf16 MFMA GEMM (3-term), plane-split operands (unchanged from r13).
// Blocks [512,576) in mode 0 run the counting sort.
// ---------------------------------------------------------------------------
__global__ __launch_bounds__(256) void gemm_pk(const unsigned short* __restrict__ Apk,
                                               const unsigned short* __restrict__ BT,
                                               const float* __restrict__ bias,
                                               void* __restrict__ Cout, int mode,
                                               const int* __restrict__ loc2,
                                               int* __restrict__ st) {
    __shared__ __align__(16) unsigned int As[64 * 32];
    __shared__ __align__(16) unsigned int Bs[64 * 32];
    const int bid = blockIdx.x;
    const int tid = threadIdx.x;

    if (bid >= 512) {
        // ================= counting sort path (overlaps v-GEMM) ============
        int gid = bid - 512;                  // = bh*4 + r
        int r = gid & 3, bh = gid >> 2;
        int* hist = (int*)As;                 // [32][32]
        int* off  = (int*)As + 1024;          // [32][32]
        int* base = (int*)Bs;                 // [32]
        const int lane = tid & 63, wvi = tid >> 6;
        const unsigned long long lower_mask =
            (lane == 0) ? 0ull : ((~0ull) >> (64 - lane));
        int myb[8], myrank[8];
#pragma unroll
        for (int si = 0; si < 8; ++si) {
            int seg = wvi * 8 + si;
            int p = seg * 64 + lane;
            int b = loc2[(size_t)(bh * 2048 + p) * 4 + r];
            myb[si] = b;
            myrank[si] = 0;
#pragma unroll 1
            for (int bkt = 0; bkt < 32; ++bkt) {
                unsigned long long m = __ballot(b == bkt);
                if (b == bkt) myrank[si] = __popcll(m & lower_mask);
                if (lane == bkt) hist[seg * 32 + bkt] = __popcll(m);
            }
        }
        __syncthreads();
        if (tid < 32) {
            int running = 0;
#pragma unroll 1
            for (int seg = 0; seg < 32; ++seg) {
                off[seg * 32 + tid] = running;
                running += hist[seg * 32 + tid];
            }
            base[tid] = running;
        }
        __syncthreads();
        if (tid == 0) {
            int a2 = 0;
#pragma unroll 1
            for (int b = 0; b < 32; ++b) { int h = base[b]; base[b] = a2; a2 += h; }
        }
        __syncthreads();
#pragma unroll
        for (int si = 0; si < 8; ++si) {
            int seg = wvi * 8 + si;
            int p = seg * 64 + lane;
            int b = myb[si];
            st[(size_t)gid * 2048 + base[b] + off[seg * 32 + b] + myrank[si]] = p;
        }
        return;
    }

    // ================= GEMM path =================
    const int m0 = (bid & 63) * 64;
    const int n0 = (bid >> 6) * 64;
    const int lane = tid & 63, wv = tid >> 6;
    const int lx = lane & 15, fg = lane >> 4;
    const int wbase = tid & ~63;           // wave-uniform qi base (u=0)
    f32x4 acc[4] = {{0.f,0.f,0.f,0.f},{0.f,0.f,0.f,0.f},{0.f,0.f,0.f,0.f},{0.f,0.f,0.f,0.f}};
    for (int k0 = 0; k0 < 512; k0 += 32) {
#pragma unroll
        for (int u = 0; u < 2; ++u) {
            int qi = u * 256 + tid;
            int row = qi >> 3, sl = qi & 7;
            int ssl = sl ^ (row & 7);              // pre-swizzled source slot
            int offp = (ssl < 4) ? (k0 + ssl * 8) : (512 + k0 + (ssl - 4) * 8);
            gload_lds16(Apk + (size_t)(m0 + row) * 1024 + offp,
                        &As[(u * 256 + wbase) * 4]);
            gload_lds16(BT + (size_t)(n0 + row) * 1024 + offp,
                        &Bs[(u * 256 + wbase) * 4]);
        }
        __syncthreads();
        int arow = wv * 16 + lx;
        short8 Ah = __builtin_bit_cast(short8,
            *(uint4*)(&As[arow * 32 + ((fg ^ (arow & 7)) << 2)]));
        short8 Al = __builtin_bit_cast(short8,
            *(uint4*)(&As[arow * 32 + (((4 + fg) ^ (arow & 7)) << 2)]));
#pragma unroll
        for (int j = 0; j < 4; ++j) {
            int brow = j * 16 + lx;
            short8 Bh2 = __builtin_bit_cast(short8,
                *(uint4*)(&Bs[brow * 32 + ((fg ^ (brow & 7)) << 2)]));
            short8 Bl2 = __builtin_bit_cast(short8,
                *(uint4*)(&Bs[brow * 32 + (((4 + fg) ^ (brow & 7)) << 2)]));
            acc[j] = __builtin_amdgcn_mfma_f32_16x16x32_bf16(Ah, Bh2, acc[j], 0, 0, 0);
            acc[j] = __builtin_amdgcn_mfma_f32_16x16x32_bf16(Ah, Bl2, acc[j], 0, 0, 0);
            acc[j] = __builtin_amdgcn_mfma_f32_16x16x32_bf16(Al, Bh2, acc[j], 0, 0, 0);
        }
        __syncthreads();
    }
#pragma unroll
    for (int j = 0; j < 4; ++j) {
        int nn = n0 + j * 16 + lx;
        float bs = bias[nn];
#pragma unroll
        for (int reg = 0; reg < 4; ++reg) {
            int m = m0 + wv * 16 + fg * 4 + reg;
            float val = acc[j][reg] + bs;
            if (mode == 0) {
                int b = m >> 11, ss = m & 2047;
                int hh = nn >> 6, f = nn & 63;
                ((unsigned short*)Cout)[((size_t)(((b << 3) + hh) * 2048 + ss)) * 64 + f] =
                    (unsigned short)f2bf(val);
            } else {
                ((float*)Cout)[(size_t)m * 512 + nn] = val;
            }
        }
    }
}

// ---------------------------------------------------------------------------
// Chunked attention v8: identical to v7 except vog is f16 (halves the 33.5MB
// intermediate write; combine reads it back as f16).
// ---------------------------------------------------------------------------
#define KSLOT(row, sl) (((row) << 6) + ((((sl) ^ ((row) & 15))) << 2))
#define PBASE 6400

__global__ __launch_bounds__(256, 3) void attn_kernel(const unsigned short* __restrict__ qkr,
                                                      const unsigned short* __restrict__ vpk,
                                                      const float* __restrict__ scaleQ,
                                                      const int* __restrict__ loc2,
                                                      const int* __restrict__ st,
                                                      float* __restrict__ lseg,
                                                      unsigned short* __restrict__ vog) {
    __shared__ __align__(16) unsigned int U[12800];  // K (12288) -> V^T + P
    __shared__ float scaleK[WS_];
    __shared__ int Tk[WS_];
    __shared__ int Lp[WS_];

    const int gid = blockIdx.x;
    const int n = gid & 31;
    const int r = (gid >> 5) & 3;
    const int bh = gid >> 7;
    const int tid = threadIdx.x;
    const int sbase = (bh * 4 + r) * 2048;
    const int lane = tid & 63;
    const int wv = tid >> 6;
    const int lx = lane & 15;
    const int hi = lane >> 4;

    if (tid < WS_) {
        int w = tid;
        int chunk = (n + 31 + (w >> 6)) & 31;
        int t = st[(size_t)sbase + chunk * 64 + (w & 63)];
        Tk[w] = t;
        int4 l4 = *(const int4*)(loc2 + (size_t)(bh * 2048 + t) * 4);
        Lp[w] = l4.x | (l4.y << 8) | (l4.z << 16) | (l4.w << 24);
        scaleK[w] = scaleQ[bh * 2048 + t];
    }
    __syncthreads();

    // ---- stage K: 192 rows x 16 granules (16B), swizzled dest
#pragma unroll
    for (int it = 0; it < 12; ++it) {
        int s = it * 256 + tid;
        int row = s >> 4, sl = s & 15;
        uint4 v4 = *(const uint4*)(qkr + ((size_t)(bh * 2048 + Tk[row])) * 128 + sl * 8);
        *(uint4*)(&U[KSLOT(row, sl)]) = v4;
    }
    __syncthreads();

    // ---- QK^T (swapped): S^T[c][q]; fragments = direct granule reads
    const int qw = 64 + wv * 16 + lx;
    short8 Bh[2], Bl[2];
#pragma unroll
    for (int ks = 0; ks < 2; ++ks) {
        Bh[ks] = __builtin_bit_cast(short8, *(uint4*)(&U[KSLOT(qw, ks * 4 + hi)]));
        Bl[ks] = __builtin_bit_cast(short8, *(uint4*)(&U[KSLOT(qw, 8 + ks * 4 + hi)]));
    }
    f32x4 s[12];
    __builtin_amdgcn_s_setprio(1);
#pragma unroll
    for (int ct = 0; ct < 12; ++ct) {
        f32x4 acc = {0.f, 0.f, 0.f, 0.f};
#pragma unroll
        for (int ks = 0; ks < 2; ++ks) {
            int arow = ct * 16 + lx;
            short8 Ah = __builtin_bit_cast(short8, *(uint4*)(&U[KSLOT(arow, ks * 4 + hi)]));
            short8 Al = __builtin_bit_cast(short8, *(uint4*)(&U[KSLOT(arow, 8 + ks * 4 + hi)]));
            acc = __builtin_amdgcn_mfma_f32_16x16x32_bf16(Ah, Bh[ks], acc, 0, 0, 0);
            acc = __builtin_amdgcn_mfma_f32_16x16x32_bf16(Ah, Bl[ks], acc, 0, 0, 0);
            acc = __builtin_amdgcn_mfma_f32_16x16x32_bf16(Al, Bh[ks], acc, 0, 0, 0);
        }
        s[ct] = acc;
    }
    __builtin_amdgcn_s_setprio(0);

    // issue V loads early (hide HBM/L2 latency under softmax)
    uint4 vl0[3], vl1[3];
#pragma unroll
    for (int it = 0; it < 3; ++it) {
        int idx = it * 256 + tid;
        int pr = idx >> 3, oct = idx & 7;
        vl0[it] = *(const uint4*)(vpk + ((size_t)(bh * 2048 + Tk[pr * 2])) * 64 + oct * 8);
        vl1[it] = *(const uint4*)(vpk + ((size_t)(bh * 2048 + Tk[pr * 2 + 1])) * 64 + oct * 8);
    }
    __syncthreads();   // K reads done; U reusable

    // ---- masks + register softmax (lane owns q = qw, 48 c-values)
    const int lq = Lp[qw];
    const unsigned int bmask = 0x80u << (r * 8);
    float mx = -3.0e38f;
#pragma unroll
    for (int ct = 0; ct < 12; ++ct) {
#pragma unroll
        for (int rr = 0; rr < 4; ++rr) {
            int c = ct * 16 + hi * 4 + rr;
            float val = s[ct][rr] * scaleK[c];
            unsigned int x = (unsigned int)(lq ^ Lp[c]);
            unsigned int z = ((x & 0x7f7f7f7fu) + 0x7f7f7f7fu) | x;
            unsigned int zm = ~z & 0x80808080u;
            int dup = __popc(zm);
            val = (c == qw) ? -100000.0f : val;
            val = (zm & bmask) ? val : NEGF;
            float ld = (dup < 2) ? 0.0f
                     : (dup == 2) ? 0.69314718f
                     : (dup == 3) ? 1.09861229f : 1.38629436f;
            val -= ld;
            s[ct][rr] = val;
            mx = fmaxf(mx, val);
        }
    }
    mx = fmaxf(mx, __shfl_xor(mx, 16));
    mx = fmaxf(mx, __shfl_xor(mx, 32));
    float ssum = 0.f;
#pragma unroll
    for (int ct = 0; ct < 12; ++ct)
#pragma unroll
        for (int rr = 0; rr < 4; ++rr) {
            float e = __expf(s[ct][rr] - mx);
            s[ct][rr] = e;
            ssum += e;
        }
    ssum += __shfl_xor(ssum, 16);
    ssum += __shfl_xor(ssum, 32);
    float lse = mx + __logf(ssum);
    if (hi == 0) lseg[(size_t)sbase + Tk[qw]] = lse;
    float inv = 1.0f / ssum;

    // ---- stage V^T bf16 into U[0..6400): word = f*100 + quad<<2 + w,
    //      quad = (c0>>3) ^ (f&7) ^ (f>>3); interleave via v_perm
#pragma unroll
    for (int it = 0; it < 3; ++it) {
        int idx = it * 256 + tid;
        int pr = idx >> 3, oct = idx & 7;
        int c0 = pr * 2;
        unsigned int aw[4] = {vl0[it].x, vl0[it].y, vl0[it].z, vl0[it].w};
        unsigned int bw[4] = {vl1[it].x, vl1[it].y, vl1[it].z, vl1[it].w};
#pragma unroll
        for (int j = 0; j < 8; ++j) {
            int f = oct * 8 + j;
            unsigned int w2 = (j & 1)
                ? __builtin_amdgcn_perm(bw[j >> 1], aw[j >> 1], 0x07060302u)
                : __builtin_amdgcn_perm(bw[j >> 1], aw[j >> 1], 0x05040100u);
            int quad = (c0 >> 3) ^ (f & 7) ^ (f >> 3);
            U[f * 100 + (quad << 2) + ((c0 & 7) >> 1)] = w2;
        }
    }
    // ---- P[q][c] bf16 into U[PBASE..): word = q*100 + ((c>>1) ^ ((q&3)<<3))
    const int q = wv * 16 + lx;
    const int pxm = (q & 3) << 3;
#pragma unroll
    for (int ct = 0; ct < 12; ++ct) {
        int po = ct * 8 + hi * 2;
        U[PBASE + q * 100 + ((po + 0) ^ pxm)] = cvtpk(s[ct][0] * inv, s[ct][1] * inv);
        U[PBASE + q * 100 + ((po + 1) ^ pxm)] = cvtpk(s[ct][2] * inv, s[ct][3] * inv);
    }
    __syncthreads();

    // ---- PV: O^T[f][q] = V^T . P^T, single-MFMA bf16
    f32x4 o[4] = {{0.f,0.f,0.f,0.f},{0.f,0.f,0.f,0.f},{0.f,0.f,0.f,0.f},{0.f,0.f,0.f,0.f}};
    const unsigned short* Uh = (const unsigned short*)U;
    __builtin_amdgcn_s_setprio(1);
#pragma unroll
    for (int ks = 0; ks < 6; ++ks) {
        short8 P8 = *(const short8*)(Uh + PBASE * 2 + q * 200 +
                                     (((ks * 16 + hi * 4) ^ pxm) << 1));
#pragma unroll
        for (int ft = 0; ft < 4; ++ft) {
            int f = ft * 16 + lx;
            int quad = (4 * ks + hi) ^ (f & 7) ^ (f >> 3);
            short8 V8 = *(const short8*)(Uh + f * 200 + (quad << 3));
            o[ft] = __builtin_amdgcn_mfma_f32_16x16x32_bf16(V8, P8, o[ft], 0, 0, 0);
        }
    }
    __builtin_amdgcn_s_setprio(0);
    const int tko = Tk[qw];
#pragma unroll
    for (int ft = 0; ft < 4; ++ft) {
        unsigned int p0, p1;
        asm("v_cvt_pkrtz_f16_f32 %0, %1, %2" : "=v"(p0) : "v"(o[ft][0]), "v"(o[ft][1]));
        asm("v_cvt_pkrtz_f16_f32 %0, %1, %2" : "=v"(p1) : "v"(o[ft][2]), "v"(o[ft][3]));
        *(uint2*)(vog + ((size_t)sbase + tko) * 64 + ft * 16 + hi * 4) = make_uint2(p0, p1);
    }
}

// ---------------------------------------------------------------------------
// Combine rounds -> PLANE-SPLIT att rows; vog read as f16.
// ---------------------------------------------------------------------------
__global__ __launch_bounds__(256) void combine_kernel(const unsigned short* __restrict__ vog,
                                                      const float* __restrict__ lseg,
                                                      unsigned short* __restrict__ attpk) {
    const int gid = blockIdx.x * 256 + threadIdx.x;   // 524288 total
    const int kq = gid & 15;          // k-quad
    const int t = (gid >> 4) & 2047;
    const int bh = gid >> 15;
    const int b = bh >> 3, h = bh & 7;
    float l[4];
    float vo[4][4];
#pragma unroll
    for (int r = 0; r < 4; ++r) {
        l[r] = lseg[(size_t)(bh * 4 + r) * 2048 + t];
        uint2 pk = *(const uint2*)(vog + ((size_t)(bh * 4 + r) * 2048 + t) * 64 + kq * 4);
        __half2 a = __builtin_bit_cast(__half2, pk.x);
        __half2 c = __builtin_bit_cast(__half2, pk.y);
        vo[r][0] = __half2float(a.x); vo[r][1] = __half2float(a.y);
        vo[r][2] = __half2float(c.x); vo[r][3] = __half2float(c.y);
    }
    float m = fmaxf(fmaxf(l[0], l[1]), fmaxf(l[2], l[3]));
    float ss = expf(l[0] - m) + expf(l[1] - m) + expf(l[2] - m) + expf(l[3] - m);
    float lt = m + logf(ss);
    float o0 = 0.f, o1 = 0.f, o2 = 0.f, o3 = 0.f;
#pragma unroll
    for (int r = 0; r < 4; ++r) {
        float w = expf(l[r] - lt);
        o0 += w * vo[r][0]; o1 += w * vo[r][1]; o2 += w * vo[r][2]; o3 += w * vo[r][3];
    }
    unsigned int h0 = f2bf(o0), h1 = f2bf(o1), h2 = f2bf(o2), h3 = f2bf(o3);
    unsigned int l0 = f2bf(o0 - __uint_as_float(h0 << 16));
    unsigned int l1 = f2bf(o1 - __uint_as_float(h1 << 16));
    unsigned int l2 = f2bf(o2 - __uint_as_float(h2 << 16));
    unsigned int l3 = f2bf(o3 - __uint_as_float(h3 << 16));
    size_t rb = ((size_t)(b * 2048 + t)) * 1024 + h * 64 + kq * 4;
    *(uint2*)(attpk + rb)       = make_uint2(h0 | (h1 << 16), h2 | (h3 << 16));
    *(uint2*)(attpk + rb + 512) = make_uint2(l0 | (l1 << 16), l2 | (l3 << 16));
}

// ---------------------------------------------------------------------------
extern "C" void kernel_launch(void* const* d_in, const int* in_sizes, int n_in,
                              void* d_out, int out_size, void* d_ws, size_t ws_size,
                              hipStream_t stream) {
    const float* x  = (const float*)d_in[0];
    const float* Wq = (const float*)d_in[1];
    const float* bq = (const float*)d_in[2];
    const float* Wv = (const float*)d_in[3];
    const float* bv = (const float*)d_in[4];
    const float* Wo = (const float*)d_in[5];
    const float* bo = (const float*)d_in[6];
    const float* hv = (const float*)d_in[7];

    unsigned int* W = (unsigned int*)d_ws;
    unsigned short* vog    = (unsigned short*)W;                // f16, [0, 4194304 u32)
    unsigned short* xpk    = (unsigned short*)(W + 4194304);    // plane-split rows
    unsigned short* qkr    = (unsigned short*)(W + 8388608);    // 32768 tokens x 256B
    unsigned short* vpk    = (unsigned short*)(W + 10485760);   // 2097152 ushort
    unsigned short* attpk  = (unsigned short*)(W + 11534336);   // 4096 rows x 2KB
    float*          scaleQ = (float*)(W + 13631488);            // 32768
    int*            loc2   = (int*)(W + 13664256);              // 131072
    int*            stbuf  = (int*)(W + 13795328);              // 131072
    float*          lseg   = (float*)(W + 13926400);            // 131072
    unsigned short* wvT    = (unsigned short*)(W + 14057472);   // 512 rows x 2KB
    unsigned short* woT    = (unsigned short*)(W + 14319616);   // 512 rows x 2KB

    dim3 blk(256);
    prep_kernel<<<2688, blk, 0, stream>>>(x, Wq, bq, hv, Wv, Wo,
                                          qkr, scaleQ, loc2, xpk, wvT, woT);
    gemm_pk<<<576, blk, 0, stream>>>(xpk, wvT, bv, (void*)vpk, 0, loc2, stbuf);
    attn_kernel<<<2048, blk, 0, stream>>>(qkr, vpk, scaleQ, loc2, stbuf, lseg, vog);
    combine_kernel<<<2048, blk, 0, stream>>>(vog, lseg, attpk);
    gemm_pk<<<512, blk, 0, stream>>>(attpk, woT, bo, d_out, 1, loc2, stbuf);
}